// Round 1
// baseline (642.301 us; speedup 1.0000x reference)
//
#include <hip/hip_runtime.h>
#include <hip/hip_bf16.h>

#define NEG_SLOPE 0.2f

// ---------------- CSR build ----------------

__global__ void count_k(const int* __restrict__ dst, int* __restrict__ counts, int E) {
    int e = blockIdx.x * blockDim.x + threadIdx.x;
    if (e < E) atomicAdd(&counts[dst[e]], 1);
}

// single-block exclusive scan: offsets[0]=0, offsets[i+1]=sum(counts[0..i])
__global__ void scan_k(const int* __restrict__ counts, int* __restrict__ offsets, int n) {
    __shared__ int s_wt[16];
    __shared__ int s_tot;
    int tid = threadIdx.x;              // 1024 threads
    int lane = tid & 63, wid = tid >> 6;
    if (tid == 0) offsets[0] = 0;
    int base = 0;
    for (int start = 0; start < n; start += 1024) {
        int i = start + tid;
        int v = (i < n) ? counts[i] : 0;
        int incl = v;
        #pragma unroll
        for (int o = 1; o < 64; o <<= 1) {
            int t = __shfl_up(incl, o);
            if (lane >= o) incl += t;
        }
        if (lane == 63) s_wt[wid] = incl;
        __syncthreads();
        if (tid == 0) {
            int r = 0;
            #pragma unroll
            for (int w = 0; w < 16; w++) { int t = s_wt[w]; s_wt[w] = r; r += t; }
            s_tot = r;
        }
        __syncthreads();
        if (i < n) offsets[i + 1] = base + s_wt[wid] + incl;
        base += s_tot;
        __syncthreads();   // protect s_wt/s_tot before next iteration overwrites
    }
}

__global__ void fill_csr_k(const int* __restrict__ src, const int* __restrict__ dst,
                           const int* __restrict__ offsets, int* __restrict__ cursor,
                           int* __restrict__ csr_src, int E) {
    int e = blockIdx.x * blockDim.x + threadIdx.x;
    if (e < E) {
        int d = dst[e];
        int pos = atomicAdd(&cursor[d], 1);
        csr_src[offsets[d] + pos] = src[e];
    }
}

// ---------------- fp32 tiled GEMM: C[M,Nc] = A[M,K] @ B[K,Nc] ----------------
// BM=128, BN=64, BK=16, 256 threads, 8x4 microtile. Nc must be multiple of 64,
// K multiple of 16. Row-guard on M.

#define BM 128
#define BN 64
#define BK 16

__global__ __launch_bounds__(256) void gemm_k(const float* __restrict__ A,
                                              const float* __restrict__ B,
                                              float* __restrict__ C,
                                              int M, int K, int Nc) {
    __shared__ float As[BK][BM];
    __shared__ float Bs[BK][BN];
    const int tid = threadIdx.x;
    const int row0 = blockIdx.x * BM;
    const int col0 = blockIdx.y * BN;

    const int a_m = tid >> 1;            // 0..127
    const int a_k = (tid & 1) * 8;       // 0 or 8
    const int b_k = tid >> 4;            // 0..15
    const int b_n = (tid & 15) * 4;      // 0..60

    const int tm0 = (tid >> 4) * 8;      // 0..120
    const int tn0 = (tid & 15) * 4;      // 0..60

    float acc[8][4];
    #pragma unroll
    for (int i = 0; i < 8; i++)
        #pragma unroll
        for (int j = 0; j < 4; j++) acc[i][j] = 0.f;

    const bool a_valid = (row0 + a_m) < M;
    for (int k0 = 0; k0 < K; k0 += BK) {
        float4 av0, av1;
        if (a_valid) {
            const float* ap = &A[(size_t)(row0 + a_m) * K + k0 + a_k];
            av0 = *(const float4*)(ap);
            av1 = *(const float4*)(ap + 4);
        } else {
            av0 = float4{0.f, 0.f, 0.f, 0.f};
            av1 = float4{0.f, 0.f, 0.f, 0.f};
        }
        As[a_k + 0][a_m] = av0.x; As[a_k + 1][a_m] = av0.y;
        As[a_k + 2][a_m] = av0.z; As[a_k + 3][a_m] = av0.w;
        As[a_k + 4][a_m] = av1.x; As[a_k + 5][a_m] = av1.y;
        As[a_k + 6][a_m] = av1.z; As[a_k + 7][a_m] = av1.w;

        float4 bv = *(const float4*)&B[(size_t)(k0 + b_k) * Nc + col0 + b_n];
        *(float4*)&Bs[b_k][b_n] = bv;
        __syncthreads();

        #pragma unroll
        for (int k = 0; k < BK; k++) {
            float ar[8], br[4];
            #pragma unroll
            for (int i = 0; i < 8; i++) ar[i] = As[k][tm0 + i];
            #pragma unroll
            for (int j = 0; j < 4; j++) br[j] = Bs[k][tn0 + j];
            #pragma unroll
            for (int i = 0; i < 8; i++)
                #pragma unroll
                for (int j = 0; j < 4; j++)
                    acc[i][j] = fmaf(ar[i], br[j], acc[i][j]);
        }
        __syncthreads();
    }

    #pragma unroll
    for (int i = 0; i < 8; i++) {
        int r = row0 + tm0 + i;
        if (r < M) {
            float4 o4{acc[i][0], acc[i][1], acc[i][2], acc[i][3]};
            *(float4*)&C[(size_t)r * Nc + col0 + tn0] = o4;
        }
    }
}

// ---------------- el/er: per-node attention dots ----------------
// one wave per node; block = 4 waves

template <int H, int D>
__global__ __launch_bounds__(256) void eler_k(const float* __restrict__ ft,
                                              const float* __restrict__ attn_l,
                                              const float* __restrict__ attn_r,
                                              float* __restrict__ el,
                                              float* __restrict__ er, int n_nodes) {
    constexpr int HD = H * D;
    __shared__ float s_al[HD], s_ar[HD];
    const int tid = threadIdx.x;
    for (int i = tid; i < HD; i += 256) { s_al[i] = attn_l[i]; s_ar[i] = attn_r[i]; }
    __syncthreads();
    const int lane = tid & 63, wid = tid >> 6;
    const int n = blockIdx.x * 4 + wid;
    if (n >= n_nodes) return;
    #pragma unroll
    for (int h = 0; h < H; h++) {
        float vl = 0.f, vr = 0.f;
        #pragma unroll
        for (int d = lane; d < D; d += 64) {
            float f = ft[(size_t)n * HD + h * D + d];
            vl = fmaf(f, s_al[h * D + d], vl);
            vr = fmaf(f, s_ar[h * D + d], vr);
        }
        #pragma unroll
        for (int o = 32; o > 0; o >>= 1) {
            vl += __shfl_down(vl, o);
            vr += __shfl_down(vr, o);
        }
        if (lane == 0) { el[n * H + h] = vl; er[n * H + h] = vr; }
    }
}

// ---------------- aggregation: softmax over in-edges + weighted gather-sum ----
// one block per dst node, blockDim = H*D (one thread per output channel)

template <int H, int D, bool RELU>
__global__ void agg_k(const float* __restrict__ ft, const float* __restrict__ el,
                      const float* __restrict__ er, const int* __restrict__ offsets,
                      const int* __restrict__ csr_src, const float* __restrict__ bias,
                      float* __restrict__ out) {
    constexpr int HD = H * D;
    constexpr int NW = HD / 64;
    constexpr int CH = 64;  // edge chunk for pass 3
    const int n = blockIdx.x;
    const int tid = threadIdx.x;
    const int lane = tid & 63, wid = tid >> 6;
    const int off = offsets[n];
    const int deg = offsets[n + 1] - off;

    __shared__ float s_er[H], s_m[H], s_inv[H];
    __shared__ float s_a[CH * H];
    __shared__ int   s_src[CH];
    __shared__ float s_red[NW * H];

    if (tid < H) s_er[tid] = er[n * H + tid];
    __syncthreads();
    float ern[H];
    #pragma unroll
    for (int h = 0; h < H; h++) ern[h] = s_er[h];

    // ---- pass 1: per-head max ----
    float lm[H];
    #pragma unroll
    for (int h = 0; h < H; h++) lm[h] = -1e30f;
    for (int i = tid; i < deg; i += HD) {
        int s = csr_src[off + i];
        #pragma unroll
        for (int h = 0; h < H; h++) {
            float e = el[s * H + h] + ern[h];
            e = e > 0.f ? e : NEG_SLOPE * e;
            lm[h] = fmaxf(lm[h], e);
        }
    }
    #pragma unroll
    for (int h = 0; h < H; h++) {
        #pragma unroll
        for (int o = 32; o > 0; o >>= 1) lm[h] = fmaxf(lm[h], __shfl_down(lm[h], o));
    }
    if (lane == 0) {
        #pragma unroll
        for (int h = 0; h < H; h++) s_red[wid * H + h] = lm[h];
    }
    __syncthreads();
    if (tid < H) {
        float m = s_red[tid];
        #pragma unroll
        for (int w = 1; w < NW; w++) m = fmaxf(m, s_red[w * H + tid]);
        s_m[tid] = m;
    }
    __syncthreads();
    float mh[H];
    #pragma unroll
    for (int h = 0; h < H; h++) mh[h] = s_m[h];
    __syncthreads();  // s_red about to be reused

    // ---- pass 2: per-head sum of exp ----
    float ls[H];
    #pragma unroll
    for (int h = 0; h < H; h++) ls[h] = 0.f;
    for (int i = tid; i < deg; i += HD) {
        int s = csr_src[off + i];
        #pragma unroll
        for (int h = 0; h < H; h++) {
            float e = el[s * H + h] + ern[h];
            e = e > 0.f ? e : NEG_SLOPE * e;
            ls[h] += expf(e - mh[h]);
        }
    }
    #pragma unroll
    for (int h = 0; h < H; h++) {
        #pragma unroll
        for (int o = 32; o > 0; o >>= 1) ls[h] += __shfl_down(ls[h], o);
    }
    if (lane == 0) {
        #pragma unroll
        for (int h = 0; h < H; h++) s_red[wid * H + h] = ls[h];
    }
    __syncthreads();
    if (tid < H) {
        float s = s_red[tid];
        #pragma unroll
        for (int w = 1; w < NW; w++) s += s_red[w * H + tid];
        s_inv[tid] = (s > 0.f) ? (1.f / s) : 0.f;
    }
    __syncthreads();
    float invh[H];
    #pragma unroll
    for (int h = 0; h < H; h++) invh[h] = s_inv[h];

    // ---- pass 3: chunked attention + gather-accumulate ----
    const int h_of = tid / D;   // uniform per wave
    float acc = 0.f;
    for (int base = 0; base < deg; base += CH) {
        int cnt = min(CH, deg - base);
        __syncthreads();   // protect s_a/s_src from previous chunk's readers
        for (int j = tid; j < cnt * H; j += HD) {
            int i = j / H, h = j % H;
            int s = csr_src[off + base + i];
            if (h == 0) s_src[i] = s;
            float e = el[s * H + h] + ern[h];
            e = e > 0.f ? e : NEG_SLOPE * e;
            s_a[i * H + h] = expf(e - mh[h]) * invh[h];
        }
        __syncthreads();
        int i = 0;
        for (; i + 4 <= cnt; i += 4) {
            float a0 = s_a[(i + 0) * H + h_of];
            float a1 = s_a[(i + 1) * H + h_of];
            float a2 = s_a[(i + 2) * H + h_of];
            float a3 = s_a[(i + 3) * H + h_of];
            float f0 = ft[(size_t)s_src[i + 0] * HD + tid];
            float f1 = ft[(size_t)s_src[i + 1] * HD + tid];
            float f2 = ft[(size_t)s_src[i + 2] * HD + tid];
            float f3 = ft[(size_t)s_src[i + 3] * HD + tid];
            acc = fmaf(a0, f0, acc);
            acc = fmaf(a1, f1, acc);
            acc = fmaf(a2, f2, acc);
            acc = fmaf(a3, f3, acc);
        }
        for (; i < cnt; i++) {
            float a = s_a[i * H + h_of];
            acc = fmaf(a, ft[(size_t)s_src[i] * HD + tid], acc);
        }
    }

    float v = acc + bias[tid];
    if (RELU) v = fmaxf(v, 0.f);
    out[(size_t)n * HD + tid] = v;
}

// ---------------- launch ----------------

extern "C" void kernel_launch(void* const* d_in, const int* in_sizes, int n_in,
                              void* d_out, int out_size, void* d_ws, size_t ws_size,
                              hipStream_t stream) {
    const float* feat    = (const float*)d_in[0];
    const int*   src     = (const int*)d_in[1];
    const int*   dst     = (const int*)d_in[2];
    const float* W1      = (const float*)d_in[3];
    const float* attn_l1 = (const float*)d_in[4];
    const float* attn_r1 = (const float*)d_in[5];
    const float* bias1   = (const float*)d_in[6];
    const float* W2      = (const float*)d_in[7];
    const float* attn_l2 = (const float*)d_in[8];
    const float* attn_r2 = (const float*)d_in[9];
    const float* bias2   = (const float*)d_in[10];
    float* out = (float*)d_out;

    const int N = in_sizes[0] / 256;   // 50000
    const int E = in_sizes[1];         // 800000

    // workspace carve-up (256B aligned)
    char* ws = (char*)d_ws;
    size_t o = 0;
    auto alloc = [&](size_t bytes) -> void* {
        void* p = ws + o;
        o = (o + bytes + 255) & ~(size_t)255;
        return p;
    };
    int* counts  = (int*)alloc((size_t)2 * N * 4);  // counts + cursor contiguous
    int* cursor  = counts + N;
    int* offsets = (int*)alloc((size_t)(N + 1) * 4);
    int* csr_src = (int*)alloc((size_t)E * 4);
    float* el1 = (float*)alloc((size_t)N * 4 * 4);
    float* er1 = (float*)alloc((size_t)N * 4 * 4);
    float* el2 = (float*)alloc((size_t)N * 4);
    float* er2 = (float*)alloc((size_t)N * 4);
    float* ft1 = (float*)alloc((size_t)N * 256 * 4);
    float* h1  = (float*)alloc((size_t)N * 256 * 4);
    float* ft2 = ft1;  // reuse: ft1 dead after layer-1 aggregation

    // CSR build
    hipMemsetAsync(counts, 0, (size_t)2 * N * 4, stream);
    count_k<<<(E + 255) / 256, 256, 0, stream>>>(dst, counts, E);
    scan_k<<<1, 1024, 0, stream>>>(counts, offsets, N);
    fill_csr_k<<<(E + 255) / 256, 256, 0, stream>>>(src, dst, offsets, cursor, csr_src, E);

    // layer 1: H=4, D=64
    gemm_k<<<dim3((N + BM - 1) / BM, 256 / BN), 256, 0, stream>>>(feat, W1, ft1, N, 256, 256);
    eler_k<4, 64><<<(N + 3) / 4, 256, 0, stream>>>(ft1, attn_l1, attn_r1, el1, er1, N);
    agg_k<4, 64, true><<<N, 256, 0, stream>>>(ft1, el1, er1, offsets, csr_src, bias1, h1);

    // layer 2: H=1, D=128
    gemm_k<<<dim3((N + BM - 1) / BM, 128 / BN), 256, 0, stream>>>(h1, W2, ft2, N, 256, 128);
    eler_k<1, 128><<<(N + 3) / 4, 256, 0, stream>>>(ft2, attn_l2, attn_r2, el2, er2, N);
    agg_k<1, 128, false><<<N, 128, 0, stream>>>(ft2, el2, er2, offsets, csr_src, bias2, out);
}

// Round 2
// 617.614 us; speedup vs baseline: 1.0400x; 1.0400x over previous
//
#include <hip/hip_runtime.h>
#include <hip/hip_bf16.h>

#define NEG_SLOPE 0.2f

// ---------------- CSR build ----------------

__global__ void count_k(const int* __restrict__ dst, int* __restrict__ counts, int E) {
    int e = blockIdx.x * blockDim.x + threadIdx.x;
    if (e < E) atomicAdd(&counts[dst[e]], 1);
}

// single-block exclusive scan: offsets[0]=0, offsets[i+1]=sum(counts[0..i])
__global__ void scan_k(const int* __restrict__ counts, int* __restrict__ offsets, int n) {
    __shared__ int s_wt[16];
    __shared__ int s_tot;
    int tid = threadIdx.x;              // 1024 threads
    int lane = tid & 63, wid = tid >> 6;
    if (tid == 0) offsets[0] = 0;
    int base = 0;
    for (int start = 0; start < n; start += 1024) {
        int i = start + tid;
        int v = (i < n) ? counts[i] : 0;
        int incl = v;
        #pragma unroll
        for (int o = 1; o < 64; o <<= 1) {
            int t = __shfl_up(incl, o);
            if (lane >= o) incl += t;
        }
        if (lane == 63) s_wt[wid] = incl;
        __syncthreads();
        if (tid == 0) {
            int r = 0;
            #pragma unroll
            for (int w = 0; w < 16; w++) { int t = s_wt[w]; s_wt[w] = r; r += t; }
            s_tot = r;
        }
        __syncthreads();
        if (i < n) offsets[i + 1] = base + s_wt[wid] + incl;
        base += s_tot;
        __syncthreads();
    }
}

__global__ void fill_csr_k(const int* __restrict__ src, const int* __restrict__ dst,
                           const int* __restrict__ offsets, int* __restrict__ cursor,
                           int* __restrict__ csr_src, int E) {
    int e = blockIdx.x * blockDim.x + threadIdx.x;
    if (e < E) {
        int d = dst[e];
        int pos = atomicAdd(&cursor[d], 1);
        csr_src[offsets[d] + pos] = src[e];
    }
}

// ---------------- fp32 tiled GEMM: C[M,Nc] = A[M,K] @ B[K,Nc] ----------------

#define BM 128
#define BN 64
#define BK 16

__global__ __launch_bounds__(256) void gemm_k(const float* __restrict__ A,
                                              const float* __restrict__ B,
                                              float* __restrict__ C,
                                              int M, int K, int Nc) {
    __shared__ float As[BK][BM];
    __shared__ float Bs[BK][BN];
    const int tid = threadIdx.x;
    const int row0 = blockIdx.x * BM;
    const int col0 = blockIdx.y * BN;

    const int a_m = tid >> 1;            // 0..127
    const int a_k = (tid & 1) * 8;       // 0 or 8
    const int b_k = tid >> 4;            // 0..15
    const int b_n = (tid & 15) * 4;      // 0..60

    const int tm0 = (tid >> 4) * 8;      // 0..120
    const int tn0 = (tid & 15) * 4;      // 0..60

    float acc[8][4];
    #pragma unroll
    for (int i = 0; i < 8; i++)
        #pragma unroll
        for (int j = 0; j < 4; j++) acc[i][j] = 0.f;

    const bool a_valid = (row0 + a_m) < M;
    for (int k0 = 0; k0 < K; k0 += BK) {
        float4 av0, av1;
        if (a_valid) {
            const float* ap = &A[(size_t)(row0 + a_m) * K + k0 + a_k];
            av0 = *(const float4*)(ap);
            av1 = *(const float4*)(ap + 4);
        } else {
            av0 = float4{0.f, 0.f, 0.f, 0.f};
            av1 = float4{0.f, 0.f, 0.f, 0.f};
        }
        As[a_k + 0][a_m] = av0.x; As[a_k + 1][a_m] = av0.y;
        As[a_k + 2][a_m] = av0.z; As[a_k + 3][a_m] = av0.w;
        As[a_k + 4][a_m] = av1.x; As[a_k + 5][a_m] = av1.y;
        As[a_k + 6][a_m] = av1.z; As[a_k + 7][a_m] = av1.w;

        float4 bv = *(const float4*)&B[(size_t)(k0 + b_k) * Nc + col0 + b_n];
        *(float4*)&Bs[b_k][b_n] = bv;
        __syncthreads();

        #pragma unroll
        for (int k = 0; k < BK; k++) {
            float ar[8], br[4];
            #pragma unroll
            for (int i = 0; i < 8; i++) ar[i] = As[k][tm0 + i];
            #pragma unroll
            for (int j = 0; j < 4; j++) br[j] = Bs[k][tn0 + j];
            #pragma unroll
            for (int i = 0; i < 8; i++)
                #pragma unroll
                for (int j = 0; j < 4; j++)
                    acc[i][j] = fmaf(ar[i], br[j], acc[i][j]);
        }
        __syncthreads();
    }

    #pragma unroll
    for (int i = 0; i < 8; i++) {
        int r = row0 + tm0 + i;
        if (r < M) {
            float4 o4{acc[i][0], acc[i][1], acc[i][2], acc[i][3]};
            *(float4*)&C[(size_t)r * Nc + col0 + tn0] = o4;
        }
    }
}

// ---------------- el/er: per-node attention dots ----------------

template <int H, int D>
__global__ __launch_bounds__(256) void eler_k(const float* __restrict__ ft,
                                              const float* __restrict__ attn_l,
                                              const float* __restrict__ attn_r,
                                              float* __restrict__ el,
                                              float* __restrict__ er, int n_nodes) {
    constexpr int HD = H * D;
    __shared__ float s_al[HD], s_ar[HD];
    const int tid = threadIdx.x;
    for (int i = tid; i < HD; i += 256) { s_al[i] = attn_l[i]; s_ar[i] = attn_r[i]; }
    __syncthreads();
    const int lane = tid & 63, wid = tid >> 6;
    const int n = blockIdx.x * 4 + wid;
    if (n >= n_nodes) return;
    #pragma unroll
    for (int h = 0; h < H; h++) {
        float vl = 0.f, vr = 0.f;
        #pragma unroll
        for (int d = lane; d < D; d += 64) {
            float f = ft[(size_t)n * HD + h * D + d];
            vl = fmaf(f, s_al[h * D + d], vl);
            vr = fmaf(f, s_ar[h * D + d], vr);
        }
        #pragma unroll
        for (int o = 32; o > 0; o >>= 1) {
            vl += __shfl_down(vl, o);
            vr += __shfl_down(vr, o);
        }
        if (lane == 0) { el[n * H + h] = vl; er[n * H + h] = vr; }
    }
}

// ---------------- edge softmax: one wave per node, writes normalized a[E,H] ----

template <int H>
__global__ __launch_bounds__(256) void attn_k(const float* __restrict__ el,
                                              const float* __restrict__ er,
                                              const int* __restrict__ offsets,
                                              const int* __restrict__ csr_src,
                                              float* __restrict__ a, int n_nodes) {
    const int lane = threadIdx.x & 63;
    const int n = blockIdx.x * 4 + (threadIdx.x >> 6);
    if (n >= n_nodes) return;
    const int off = offsets[n];
    const int deg = offsets[n + 1] - off;
    if (deg == 0) return;

    float ern[H];
    #pragma unroll
    for (int h = 0; h < H; h++) ern[h] = er[n * H + h];

    // pass 1: per-head max of leaky(el[src]+er[n])
    float m[H];
    #pragma unroll
    for (int h = 0; h < H; h++) m[h] = -1e30f;
    for (int base = 0; base < deg; base += 64) {
        int i = base + lane;
        if (i < deg) {
            int s = csr_src[off + i];
            if constexpr (H == 4) {
                float4 ev = ((const float4*)el)[s];
                float e[4] = {ev.x, ev.y, ev.z, ev.w};
                #pragma unroll
                for (int h = 0; h < 4; h++) {
                    float t = e[h] + ern[h];
                    t = t > 0.f ? t : NEG_SLOPE * t;
                    m[h] = fmaxf(m[h], t);
                }
            } else {
                float t = el[s] + ern[0];
                t = t > 0.f ? t : NEG_SLOPE * t;
                m[0] = fmaxf(m[0], t);
            }
        }
    }
    #pragma unroll
    for (int h = 0; h < H; h++)
        #pragma unroll
        for (int o = 32; o > 0; o >>= 1) m[h] = fmaxf(m[h], __shfl_xor(m[h], o));

    // pass 2: per-head sum of exp
    float ssum[H];
    #pragma unroll
    for (int h = 0; h < H; h++) ssum[h] = 0.f;
    for (int base = 0; base < deg; base += 64) {
        int i = base + lane;
        if (i < deg) {
            int s = csr_src[off + i];
            if constexpr (H == 4) {
                float4 ev = ((const float4*)el)[s];
                float e[4] = {ev.x, ev.y, ev.z, ev.w};
                #pragma unroll
                for (int h = 0; h < 4; h++) {
                    float t = e[h] + ern[h];
                    t = t > 0.f ? t : NEG_SLOPE * t;
                    ssum[h] += __expf(t - m[h]);
                }
            } else {
                float t = el[s] + ern[0];
                t = t > 0.f ? t : NEG_SLOPE * t;
                ssum[0] += __expf(t - m[0]);
            }
        }
    }
    #pragma unroll
    for (int h = 0; h < H; h++)
        #pragma unroll
        for (int o = 32; o > 0; o >>= 1) ssum[h] += __shfl_xor(ssum[h], o);
    float inv[H];
    #pragma unroll
    for (int h = 0; h < H; h++) inv[h] = (ssum[h] > 0.f) ? (1.f / ssum[h]) : 0.f;

    // pass 3: write normalized attention
    for (int base = 0; base < deg; base += 64) {
        int i = base + lane;
        if (i < deg) {
            int s = csr_src[off + i];
            if constexpr (H == 4) {
                float4 ev = ((const float4*)el)[s];
                float e[4] = {ev.x, ev.y, ev.z, ev.w};
                float4 av;
                float* ap = (float*)&av;
                #pragma unroll
                for (int h = 0; h < 4; h++) {
                    float t = e[h] + ern[h];
                    t = t > 0.f ? t : NEG_SLOPE * t;
                    ap[h] = __expf(t - m[h]) * inv[h];
                }
                ((float4*)a)[off + i] = av;
            } else {
                float t = el[s] + ern[0];
                t = t > 0.f ? t : NEG_SLOPE * t;
                a[off + i] = __expf(t - m[0]) * inv[0];
            }
        }
    }
}

// ---------------- aggregation: pure gather-accumulate ----------------
// one block per dst node, blockDim = H*D (one thread per output channel)

template <int H, int D, bool RELU>
__global__ __launch_bounds__(H * D) void agg_k(const float* __restrict__ ft,
                                               const float* __restrict__ a,
                                               const int* __restrict__ offsets,
                                               const int* __restrict__ csr_src,
                                               const float* __restrict__ bias,
                                               float* __restrict__ out) {
    constexpr int HD = H * D;
    constexpr int MAXE = 128;   // edge chunk staged in LDS
    const int n = blockIdx.x;
    const int tid = threadIdx.x;
    const int off = offsets[n];
    const int deg = offsets[n + 1] - off;
    const int h_of = tid / D;   // wave-uniform

    __shared__ int   s_src[MAXE];
    __shared__ float s_a[MAXE * H];

    float acc = 0.f;
    for (int base = 0; base < deg; base += MAXE) {
        int cnt = min(MAXE, deg - base);
        if (base) __syncthreads();
        for (int j = tid; j < cnt; j += HD) s_src[j] = csr_src[off + base + j];
        for (int j = tid; j < cnt * H; j += HD) s_a[j] = a[(size_t)(off + base) * H + j];
        __syncthreads();

        int i = 0;
        for (; i + 8 <= cnt; i += 8) {
            int s0 = s_src[i + 0], s1 = s_src[i + 1], s2 = s_src[i + 2], s3 = s_src[i + 3];
            int s4 = s_src[i + 4], s5 = s_src[i + 5], s6 = s_src[i + 6], s7 = s_src[i + 7];
            float w0 = s_a[(i + 0) * H + h_of], w1 = s_a[(i + 1) * H + h_of];
            float w2 = s_a[(i + 2) * H + h_of], w3 = s_a[(i + 3) * H + h_of];
            float w4 = s_a[(i + 4) * H + h_of], w5 = s_a[(i + 5) * H + h_of];
            float w6 = s_a[(i + 6) * H + h_of], w7 = s_a[(i + 7) * H + h_of];
            float f0 = ft[(size_t)s0 * HD + tid];
            float f1 = ft[(size_t)s1 * HD + tid];
            float f2 = ft[(size_t)s2 * HD + tid];
            float f3 = ft[(size_t)s3 * HD + tid];
            float f4 = ft[(size_t)s4 * HD + tid];
            float f5 = ft[(size_t)s5 * HD + tid];
            float f6 = ft[(size_t)s6 * HD + tid];
            float f7 = ft[(size_t)s7 * HD + tid];
            acc = fmaf(w0, f0, acc); acc = fmaf(w1, f1, acc);
            acc = fmaf(w2, f2, acc); acc = fmaf(w3, f3, acc);
            acc = fmaf(w4, f4, acc); acc = fmaf(w5, f5, acc);
            acc = fmaf(w6, f6, acc); acc = fmaf(w7, f7, acc);
        }
        for (; i < cnt; i++)
            acc = fmaf(s_a[i * H + h_of], ft[(size_t)s_src[i] * HD + tid], acc);
    }

    float v = acc + bias[tid];
    if (RELU) v = fmaxf(v, 0.f);
    out[(size_t)n * HD + tid] = v;
}

// ---------------- launch ----------------

extern "C" void kernel_launch(void* const* d_in, const int* in_sizes, int n_in,
                              void* d_out, int out_size, void* d_ws, size_t ws_size,
                              hipStream_t stream) {
    const float* feat    = (const float*)d_in[0];
    const int*   src     = (const int*)d_in[1];
    const int*   dst     = (const int*)d_in[2];
    const float* W1      = (const float*)d_in[3];
    const float* attn_l1 = (const float*)d_in[4];
    const float* attn_r1 = (const float*)d_in[5];
    const float* bias1   = (const float*)d_in[6];
    const float* W2      = (const float*)d_in[7];
    const float* attn_l2 = (const float*)d_in[8];
    const float* attn_r2 = (const float*)d_in[9];
    const float* bias2   = (const float*)d_in[10];
    float* out = (float*)d_out;

    const int N = in_sizes[0] / 256;   // 50000
    const int E = in_sizes[1];         // 800000

    char* ws = (char*)d_ws;
    size_t o = 0;
    auto alloc = [&](size_t bytes) -> void* {
        void* p = ws + o;
        o = (o + bytes + 255) & ~(size_t)255;
        return p;
    };
    int* counts  = (int*)alloc((size_t)2 * N * 4);
    int* cursor  = counts + N;
    int* offsets = (int*)alloc((size_t)(N + 1) * 4);
    int* csr_src = (int*)alloc((size_t)E * 4);
    float* el1 = (float*)alloc((size_t)N * 4 * 4);
    float* er1 = (float*)alloc((size_t)N * 4 * 4);
    float* el2 = (float*)alloc((size_t)N * 4);
    float* er2 = (float*)alloc((size_t)N * 4);
    float* a_buf = (float*)alloc((size_t)E * 4 * 4);  // reused by both layers
    float* ft1 = (float*)alloc((size_t)N * 256 * 4);
    float* h1  = (float*)alloc((size_t)N * 256 * 4);
    float* ft2 = ft1;  // ft1 dead after layer-1 aggregation

    // CSR build
    hipMemsetAsync(counts, 0, (size_t)2 * N * 4, stream);
    count_k<<<(E + 255) / 256, 256, 0, stream>>>(dst, counts, E);
    scan_k<<<1, 1024, 0, stream>>>(counts, offsets, N);
    fill_csr_k<<<(E + 255) / 256, 256, 0, stream>>>(src, dst, offsets, cursor, csr_src, E);

    // layer 1: H=4, D=64
    gemm_k<<<dim3((N + BM - 1) / BM, 256 / BN), 256, 0, stream>>>(feat, W1, ft1, N, 256, 256);
    eler_k<4, 64><<<(N + 3) / 4, 256, 0, stream>>>(ft1, attn_l1, attn_r1, el1, er1, N);
    attn_k<4><<<(N + 3) / 4, 256, 0, stream>>>(el1, er1, offsets, csr_src, a_buf, N);
    agg_k<4, 64, true><<<N, 256, 0, stream>>>(ft1, a_buf, offsets, csr_src, bias1, h1);

    // layer 2: H=1, D=128
    gemm_k<<<dim3((N + BM - 1) / BM, 128 / BN), 256, 0, stream>>>(h1, W2, ft2, N, 256, 128);
    eler_k<1, 128><<<(N + 3) / 4, 256, 0, stream>>>(ft2, attn_l2, attn_r2, el2, er2, N);
    attn_k<1><<<(N + 3) / 4, 256, 0, stream>>>(el2, er2, offsets, csr_src, a_buf, N);
    agg_k<1, 128, false><<<N, 128, 0, stream>>>(ft2, a_buf, offsets, csr_src, bias2, out);
}

// Round 3
// 430.864 us; speedup vs baseline: 1.4907x; 1.4334x over previous
//
#include <hip/hip_runtime.h>
#include <hip/hip_bf16.h>

#define NEG_SLOPE 0.2f

typedef short s16x8 __attribute__((ext_vector_type(8)));
typedef float f32x4 __attribute__((ext_vector_type(4)));

__device__ __forceinline__ unsigned short f2bf(float f) {
    unsigned int u = __float_as_uint(f);
    unsigned int r = (u + 0x7fffu + ((u >> 16) & 1u)) >> 16;
    return (unsigned short)r;
}
__device__ __forceinline__ float bf2f(unsigned int us) {
    return __uint_as_float(us << 16);
}

// ---------------- CSR build ----------------

__global__ void count_k(const int* __restrict__ dst, int* __restrict__ counts, int E) {
    int e = blockIdx.x * blockDim.x + threadIdx.x;
    if (e < E) atomicAdd(&counts[dst[e]], 1);
}

// multi-block scan: partial sums -> 1-wave scan of partials -> scanned write
__global__ __launch_bounds__(1024) void partial_k(const int* __restrict__ counts,
                                                  int* __restrict__ part, int n) {
    __shared__ int s[16];
    int tid = threadIdx.x, lane = tid & 63, wid = tid >> 6;
    int i = blockIdx.x * 1024 + tid;
    int v = (i < n) ? counts[i] : 0;
    #pragma unroll
    for (int o = 32; o > 0; o >>= 1) v += __shfl_xor(v, o);
    if (lane == 0) s[wid] = v;
    __syncthreads();
    if (tid == 0) {
        int r = 0;
        #pragma unroll
        for (int w = 0; w < 16; w++) r += s[w];
        part[blockIdx.x] = r;
    }
}

__global__ void scanpart_k(int* __restrict__ part, int nb) {  // nb <= 64, one wave
    int tid = threadIdx.x;
    int orig = (tid < nb) ? part[tid] : 0;
    int v = orig;
    #pragma unroll
    for (int o = 1; o < 64; o <<= 1) {
        int t = __shfl_up(v, o);
        if (tid >= o) v += t;
    }
    if (tid < nb) part[tid] = v - orig;   // exclusive
}

__global__ __launch_bounds__(1024) void scanwrite_k(const int* __restrict__ counts,
                                                    const int* __restrict__ part,
                                                    int* __restrict__ offsets, int n) {
    __shared__ int s_wt[16];
    int tid = threadIdx.x, lane = tid & 63, wid = tid >> 6;
    int i = blockIdx.x * 1024 + tid;
    int v = (i < n) ? counts[i] : 0;
    int incl = v;
    #pragma unroll
    for (int o = 1; o < 64; o <<= 1) {
        int t = __shfl_up(incl, o);
        if (lane >= o) incl += t;
    }
    if (lane == 63) s_wt[wid] = incl;
    __syncthreads();
    if (tid == 0) {
        int r = 0;
        #pragma unroll
        for (int w = 0; w < 16; w++) { int t = s_wt[w]; s_wt[w] = r; r += t; }
    }
    __syncthreads();
    if (i < n) offsets[i + 1] = part[blockIdx.x] + s_wt[wid] + incl;
    if (blockIdx.x == 0 && tid == 0) offsets[0] = 0;
}

__global__ void fill_csr_k(const int* __restrict__ src, const int* __restrict__ dst,
                           const int* __restrict__ offsets, int* __restrict__ cursor,
                           int* __restrict__ csr_src, int E) {
    int e = blockIdx.x * blockDim.x + threadIdx.x;
    if (e < E) {
        int d = dst[e];
        int pos = atomicAdd(&cursor[d], 1);
        csr_src[offsets[d] + pos] = src[e];
    }
}

// ---------------- split-bf16 MFMA GEMM ----------------
// C_bf16[M,Nc] = A_f32[M,K] @ B_f32[K,Nc], via hi/lo bf16 decomposition:
// C = Ahi*Bhi + Ahi*Blo + Alo*Bhi  (lo*lo dropped, ~2^-18 rel). K%32==0, Nc%64==0.
// Tile 128x64, 256 threads (2x2 waves of 64x32), 16x16x32 bf16 MFMA.

__global__ __launch_bounds__(256) void gemm_k(const float* __restrict__ A,
                                              const float* __restrict__ B,
                                              unsigned short* __restrict__ Cb,
                                              int M, int K, int Nc) {
    // +8 pad per 32-elem row -> 80B row stride, 2-way-max bank aliasing on b128 reads
    __shared__ __align__(16) unsigned short As_hi[128][40], As_lo[128][40];
    __shared__ __align__(16) unsigned short Bs_hi[64][40],  Bs_lo[64][40];

    const int tid = threadIdx.x;
    const int lane = tid & 63, wid = tid >> 6;
    const int row0 = blockIdx.x * 128;
    const int col0 = blockIdx.y * 64;
    const int wm = (wid & 1) * 64;   // wave row offset
    const int wn = (wid >> 1) * 32;  // wave col offset
    const int quad = lane >> 4, mrow = lane & 15;

    // staging coords
    const int a_r = tid >> 1;              // 0..127
    const int a_k = (tid & 1) * 16;        // 0 or 16
    const int b_k = tid >> 3;              // 0..31
    const int b_n = (tid & 7) * 8;         // 0..56
    const bool a_valid = (row0 + a_r) < M;

    f32x4 acc[4][2];
    #pragma unroll
    for (int i = 0; i < 4; i++)
        #pragma unroll
        for (int j = 0; j < 2; j++) acc[i][j] = f32x4{0.f, 0.f, 0.f, 0.f};

    for (int k0 = 0; k0 < K; k0 += 32) {
        // ---- stage A 128x32 (split) ----
        float af[16];
        if (a_valid) {
            const float* ap = &A[(size_t)(row0 + a_r) * K + k0 + a_k];
            #pragma unroll
            for (int q = 0; q < 4; q++) {
                float4 t = *(const float4*)(ap + q * 4);
                af[q * 4 + 0] = t.x; af[q * 4 + 1] = t.y;
                af[q * 4 + 2] = t.z; af[q * 4 + 3] = t.w;
            }
        } else {
            #pragma unroll
            for (int q = 0; q < 16; q++) af[q] = 0.f;
        }
        unsigned int* dh = (unsigned int*)&As_hi[a_r][a_k];
        unsigned int* dl = (unsigned int*)&As_lo[a_r][a_k];
        #pragma unroll
        for (int p = 0; p < 8; p++) {
            unsigned short h0 = f2bf(af[2 * p]), h1 = f2bf(af[2 * p + 1]);
            unsigned short l0 = f2bf(af[2 * p] - bf2f(h0));
            unsigned short l1 = f2bf(af[2 * p + 1] - bf2f(h1));
            dh[p] = (unsigned int)h0 | ((unsigned int)h1 << 16);
            dl[p] = (unsigned int)l0 | ((unsigned int)l1 << 16);
        }
        // ---- stage B 32x64 transposed to [n][k] (split) ----
        {
            const float* bp = &B[(size_t)(k0 + b_k) * Nc + col0 + b_n];
            float4 t0 = *(const float4*)(bp);
            float4 t1 = *(const float4*)(bp + 4);
            float bf[8] = {t0.x, t0.y, t0.z, t0.w, t1.x, t1.y, t1.z, t1.w};
            #pragma unroll
            for (int x = 0; x < 8; x++) {
                unsigned short h = f2bf(bf[x]);
                unsigned short l = f2bf(bf[x] - bf2f(h));
                Bs_hi[b_n + x][b_k] = h;
                Bs_lo[b_n + x][b_k] = l;
            }
        }
        __syncthreads();

        s16x8 ah[4], al[4], bh[2], bl[2];
        #pragma unroll
        for (int i = 0; i < 4; i++) {
            ah[i] = *(const s16x8*)&As_hi[wm + 16 * i + mrow][quad * 8];
            al[i] = *(const s16x8*)&As_lo[wm + 16 * i + mrow][quad * 8];
        }
        #pragma unroll
        for (int j = 0; j < 2; j++) {
            bh[j] = *(const s16x8*)&Bs_hi[wn + 16 * j + mrow][quad * 8];
            bl[j] = *(const s16x8*)&Bs_lo[wn + 16 * j + mrow][quad * 8];
        }
        #pragma unroll
        for (int i = 0; i < 4; i++)
            #pragma unroll
            for (int j = 0; j < 2; j++) {
                acc[i][j] = __builtin_amdgcn_mfma_f32_16x16x32_bf16(ah[i], bh[j], acc[i][j], 0, 0, 0);
                acc[i][j] = __builtin_amdgcn_mfma_f32_16x16x32_bf16(ah[i], bl[j], acc[i][j], 0, 0, 0);
                acc[i][j] = __builtin_amdgcn_mfma_f32_16x16x32_bf16(al[i], bh[j], acc[i][j], 0, 0, 0);
            }
        __syncthreads();
    }

    // epilogue: C/D frag layout col=lane&15, row=quad*4+r
    #pragma unroll
    for (int i = 0; i < 4; i++) {
        #pragma unroll
        for (int j = 0; j < 2; j++) {
            int col = col0 + wn + 16 * j + mrow;
            int rbase = row0 + wm + 16 * i + quad * 4;
            #pragma unroll
            for (int r = 0; r < 4; r++) {
                int row = rbase + r;
                if (row < M) Cb[(size_t)row * Nc + col] = f2bf(acc[i][j][r]);
            }
        }
    }
}

// ---------------- el/er from bf16 ft ----------------
// wave per node; lane covers HD/64 consecutive channels (stays within one head)

template <int H, int D>
__global__ __launch_bounds__(256) void eler_k(const unsigned short* __restrict__ ft,
                                              const float* __restrict__ attn_l,
                                              const float* __restrict__ attn_r,
                                              float* __restrict__ el,
                                              float* __restrict__ er, int n_nodes) {
    constexpr int HD = H * D;
    constexpr int CPL = HD / 64;   // channels per lane: 4 (H=4) or 2 (H=1)
    constexpr int G = 64 / H;      // lanes per head
    __shared__ float s_al[HD], s_ar[HD];
    const int tid = threadIdx.x;
    for (int i = tid; i < HD; i += 256) { s_al[i] = attn_l[i]; s_ar[i] = attn_r[i]; }
    __syncthreads();
    const int lane = tid & 63, wid = tid >> 6;
    const int n = blockIdx.x * 4 + wid;
    if (n >= n_nodes) return;
    const int c0 = lane * CPL;
    const int head = c0 / D;
    float f[CPL];
    if constexpr (CPL == 4) {
        uint2 u = ((const uint2*)ft)[(size_t)n * (HD / 4) + lane];
        f[0] = bf2f(u.x & 0xffff); f[1] = bf2f(u.x >> 16);
        f[2] = bf2f(u.y & 0xffff); f[3] = bf2f(u.y >> 16);
    } else {
        unsigned int u = ((const unsigned int*)ft)[(size_t)n * (HD / 2) + lane];
        f[0] = bf2f(u & 0xffff); f[1] = bf2f(u >> 16);
    }
    float vl = 0.f, vr = 0.f;
    #pragma unroll
    for (int t = 0; t < CPL; t++) {
        vl = fmaf(f[t], s_al[c0 + t], vl);
        vr = fmaf(f[t], s_ar[c0 + t], vr);
    }
    #pragma unroll
    for (int o = G / 2; o > 0; o >>= 1) {
        vl += __shfl_xor(vl, o);
        vr += __shfl_xor(vr, o);
    }
    if ((lane & (G - 1)) == 0) {
        el[n * H + head] = vl;
        er[n * H + head] = vr;
    }
}

// ---------------- edge softmax: one wave per node, writes normalized a[E,H] ----

template <int H>
__global__ __launch_bounds__(256) void attn_k(const float* __restrict__ el,
                                              const float* __restrict__ er,
                                              const int* __restrict__ offsets,
                                              const int* __restrict__ csr_src,
                                              float* __restrict__ a, int n_nodes) {
    const int lane = threadIdx.x & 63;
    const int n = blockIdx.x * 4 + (threadIdx.x >> 6);
    if (n >= n_nodes) return;
    const int off = offsets[n];
    const int deg = offsets[n + 1] - off;
    if (deg == 0) return;

    float ern[H];
    #pragma unroll
    for (int h = 0; h < H; h++) ern[h] = er[n * H + h];

    float m[H];
    #pragma unroll
    for (int h = 0; h < H; h++) m[h] = -1e30f;
    for (int base = 0; base < deg; base += 64) {
        int i = base + lane;
        if (i < deg) {
            int s = csr_src[off + i];
            if constexpr (H == 4) {
                float4 ev = ((const float4*)el)[s];
                float e[4] = {ev.x, ev.y, ev.z, ev.w};
                #pragma unroll
                for (int h = 0; h < 4; h++) {
                    float t = e[h] + ern[h];
                    t = t > 0.f ? t : NEG_SLOPE * t;
                    m[h] = fmaxf(m[h], t);
                }
            } else {
                float t = el[s] + ern[0];
                t = t > 0.f ? t : NEG_SLOPE * t;
                m[0] = fmaxf(m[0], t);
            }
        }
    }
    #pragma unroll
    for (int h = 0; h < H; h++)
        #pragma unroll
        for (int o = 32; o > 0; o >>= 1) m[h] = fmaxf(m[h], __shfl_xor(m[h], o));

    float ssum[H];
    #pragma unroll
    for (int h = 0; h < H; h++) ssum[h] = 0.f;
    for (int base = 0; base < deg; base += 64) {
        int i = base + lane;
        if (i < deg) {
            int s = csr_src[off + i];
            if constexpr (H == 4) {
                float4 ev = ((const float4*)el)[s];
                float e[4] = {ev.x, ev.y, ev.z, ev.w};
                #pragma unroll
                for (int h = 0; h < 4; h++) {
                    float t = e[h] + ern[h];
                    t = t > 0.f ? t : NEG_SLOPE * t;
                    ssum[h] += __expf(t - m[h]);
                }
            } else {
                float t = el[s] + ern[0];
                t = t > 0.f ? t : NEG_SLOPE * t;
                ssum[0] += __expf(t - m[0]);
            }
        }
    }
    #pragma unroll
    for (int h = 0; h < H; h++)
        #pragma unroll
        for (int o = 32; o > 0; o >>= 1) ssum[h] += __shfl_xor(ssum[h], o);
    float inv[H];
    #pragma unroll
    for (int h = 0; h < H; h++) inv[h] = (ssum[h] > 0.f) ? (1.f / ssum[h]) : 0.f;

    for (int base = 0; base < deg; base += 64) {
        int i = base + lane;
        if (i < deg) {
            int s = csr_src[off + i];
            if constexpr (H == 4) {
                float4 ev = ((const float4*)el)[s];
                float e[4] = {ev.x, ev.y, ev.z, ev.w};
                float4 av;
                float* ap = (float*)&av;
                #pragma unroll
                for (int h = 0; h < 4; h++) {
                    float t = e[h] + ern[h];
                    t = t > 0.f ? t : NEG_SLOPE * t;
                    ap[h] = __expf(t - m[h]) * inv[h];
                }
                ((float4*)a)[off + i] = av;
            } else {
                float t = el[s] + ern[0];
                t = t > 0.f ? t : NEG_SLOPE * t;
                a[off + i] = __expf(t - m[0]) * inv[0];
            }
        }
    }
}

// ---------------- aggregation: bf16 gather-accumulate ----------------
// one block per dst node, HD/2 threads, each thread owns 2 consecutive channels

template <int H, int D, bool RELU>
__global__ __launch_bounds__(H * D / 2) void agg_k(const unsigned short* __restrict__ ft,
                                                   const float* __restrict__ a,
                                                   const int* __restrict__ offsets,
                                                   const int* __restrict__ csr_src,
                                                   const float* __restrict__ bias,
                                                   float* __restrict__ out) {
    constexpr int HD = H * D;
    constexpr int NT = HD / 2;
    constexpr int MAXE = 128;
    const int n = blockIdx.x;
    const int tid = threadIdx.x;
    const int off = offsets[n];
    const int deg = offsets[n + 1] - off;
    const int h_of = (2 * tid) / D;   // wave-uniform
    const unsigned int* ftp = (const unsigned int*)ft;

    __shared__ int   s_src[MAXE];
    __shared__ float s_a[MAXE * H];

    float acc0 = 0.f, acc1 = 0.f;
    for (int base = 0; base < deg; base += MAXE) {
        int cnt = min(MAXE, deg - base);
        if (base) __syncthreads();
        for (int j = tid; j < cnt; j += NT) s_src[j] = csr_src[off + base + j];
        for (int j = tid; j < cnt * H; j += NT) s_a[j] = a[(size_t)(off + base) * H + j];
        __syncthreads();

        int i = 0;
        for (; i + 8 <= cnt; i += 8) {
            int s0 = s_src[i + 0], s1 = s_src[i + 1], s2 = s_src[i + 2], s3 = s_src[i + 3];
            int s4 = s_src[i + 4], s5 = s_src[i + 5], s6 = s_src[i + 6], s7 = s_src[i + 7];
            float w0 = s_a[(i + 0) * H + h_of], w1 = s_a[(i + 1) * H + h_of];
            float w2 = s_a[(i + 2) * H + h_of], w3 = s_a[(i + 3) * H + h_of];
            float w4 = s_a[(i + 4) * H + h_of], w5 = s_a[(i + 5) * H + h_of];
            float w6 = s_a[(i + 6) * H + h_of], w7 = s_a[(i + 7) * H + h_of];
            unsigned int u0 = ftp[(size_t)s0 * NT + tid];
            unsigned int u1 = ftp[(size_t)s1 * NT + tid];
            unsigned int u2 = ftp[(size_t)s2 * NT + tid];
            unsigned int u3 = ftp[(size_t)s3 * NT + tid];
            unsigned int u4 = ftp[(size_t)s4 * NT + tid];
            unsigned int u5 = ftp[(size_t)s5 * NT + tid];
            unsigned int u6 = ftp[(size_t)s6 * NT + tid];
            unsigned int u7 = ftp[(size_t)s7 * NT + tid];
            acc0 = fmaf(w0, bf2f(u0 & 0xffff), acc0); acc1 = fmaf(w0, bf2f(u0 >> 16), acc1);
            acc0 = fmaf(w1, bf2f(u1 & 0xffff), acc0); acc1 = fmaf(w1, bf2f(u1 >> 16), acc1);
            acc0 = fmaf(w2, bf2f(u2 & 0xffff), acc0); acc1 = fmaf(w2, bf2f(u2 >> 16), acc1);
            acc0 = fmaf(w3, bf2f(u3 & 0xffff), acc0); acc1 = fmaf(w3, bf2f(u3 >> 16), acc1);
            acc0 = fmaf(w4, bf2f(u4 & 0xffff), acc0); acc1 = fmaf(w4, bf2f(u4 >> 16), acc1);
            acc0 = fmaf(w5, bf2f(u5 & 0xffff), acc0); acc1 = fmaf(w5, bf2f(u5 >> 16), acc1);
            acc0 = fmaf(w6, bf2f(u6 & 0xffff), acc0); acc1 = fmaf(w6, bf2f(u6 >> 16), acc1);
            acc0 = fmaf(w7, bf2f(u7 & 0xffff), acc0); acc1 = fmaf(w7, bf2f(u7 >> 16), acc1);
        }
        for (; i < cnt; i++) {
            float w = s_a[i * H + h_of];
            unsigned int u = ftp[(size_t)s_src[i] * NT + tid];
            acc0 = fmaf(w, bf2f(u & 0xffff), acc0);
            acc1 = fmaf(w, bf2f(u >> 16), acc1);
        }
    }

    float v0 = acc0 + bias[2 * tid];
    float v1 = acc1 + bias[2 * tid + 1];
    if (RELU) { v0 = fmaxf(v0, 0.f); v1 = fmaxf(v1, 0.f); }
    ((float2*)out)[(size_t)n * NT + tid] = float2{v0, v1};
}

// ---------------- launch ----------------

extern "C" void kernel_launch(void* const* d_in, const int* in_sizes, int n_in,
                              void* d_out, int out_size, void* d_ws, size_t ws_size,
                              hipStream_t stream) {
    const float* feat    = (const float*)d_in[0];
    const int*   src     = (const int*)d_in[1];
    const int*   dst     = (const int*)d_in[2];
    const float* W1      = (const float*)d_in[3];
    const float* attn_l1 = (const float*)d_in[4];
    const float* attn_r1 = (const float*)d_in[5];
    const float* bias1   = (const float*)d_in[6];
    const float* W2      = (const float*)d_in[7];
    const float* attn_l2 = (const float*)d_in[8];
    const float* attn_r2 = (const float*)d_in[9];
    const float* bias2   = (const float*)d_in[10];
    float* out = (float*)d_out;

    const int N = in_sizes[0] / 256;   // 50000
    const int E = in_sizes[1];         // 800000
    const int NB = (N + 1023) / 1024;  // 49 (must be <= 64 for scanpart_k)

    char* ws = (char*)d_ws;
    size_t o = 0;
    auto alloc = [&](size_t bytes) -> void* {
        void* p = ws + o;
        o = (o + bytes + 255) & ~(size_t)255;
        return p;
    };
    int* counts  = (int*)alloc((size_t)2 * N * 4);
    int* cursor  = counts + N;
    int* offsets = (int*)alloc((size_t)(N + 1) * 4);
    int* part    = (int*)alloc(64 * 4);
    int* csr_src = (int*)alloc((size_t)E * 4);
    float* el1 = (float*)alloc((size_t)N * 4 * 4);
    float* er1 = (float*)alloc((size_t)N * 4 * 4);
    float* el2 = (float*)alloc((size_t)N * 4);
    float* er2 = (float*)alloc((size_t)N * 4);
    float* a_buf = (float*)alloc((size_t)E * 4 * 4);              // both layers
    unsigned short* ft1b = (unsigned short*)alloc((size_t)N * 256 * 2);
    float* h1 = (float*)alloc((size_t)N * 256 * 4);
    unsigned short* ft2b = ft1b;   // ft1b dead after layer-1 aggregation

    // CSR build
    hipMemsetAsync(counts, 0, (size_t)2 * N * 4, stream);
    count_k<<<(E + 255) / 256, 256, 0, stream>>>(dst, counts, E);
    partial_k<<<NB, 1024, 0, stream>>>(counts, part, N);
    scanpart_k<<<1, 64, 0, stream>>>(part, NB);
    scanwrite_k<<<NB, 1024, 0, stream>>>(counts, part, offsets, N);
    fill_csr_k<<<(E + 255) / 256, 256, 0, stream>>>(src, dst, offsets, cursor, csr_src, E);

    // layer 1: H=4, D=64
    gemm_k<<<dim3((N + 127) / 128, 256 / 64), 256, 0, stream>>>(feat, W1, ft1b, N, 256, 256);
    eler_k<4, 64><<<(N + 3) / 4, 256, 0, stream>>>(ft1b, attn_l1, attn_r1, el1, er1, N);
    attn_k<4><<<(N + 3) / 4, 256, 0, stream>>>(el1, er1, offsets, csr_src, a_buf, N);
    agg_k<4, 64, true><<<N, 128, 0, stream>>>(ft1b, a_buf, offsets, csr_src, bias1, h1);

    // layer 2: H=1, D=128
    gemm_k<<<dim3((N + 127) / 128, 128 / 64), 256, 0, stream>>>(h1, W2, ft2b, N, 256, 128);
    eler_k<1, 128><<<(N + 3) / 4, 256, 0, stream>>>(ft2b, attn_l2, attn_r2, el2, er2, N);
    attn_k<1><<<(N + 3) / 4, 256, 0, stream>>>(el2, er2, offsets, csr_src, a_buf, N);
    agg_k<1, 128, false><<<N, 64, 0, stream>>>(ft2b, a_buf, offsets, csr_src, bias2, out);
}

// Round 4
// 402.606 us; speedup vs baseline: 1.5954x; 1.0702x over previous
//
#include <hip/hip_runtime.h>
#include <hip/hip_bf16.h>

#define NEG_SLOPE 0.2f

typedef short s16x8 __attribute__((ext_vector_type(8)));
typedef float f32x4 __attribute__((ext_vector_type(4)));

__device__ __forceinline__ unsigned short f2bf(float f) {
    unsigned int u = __float_as_uint(f);
    unsigned int r = (u + 0x7fffu + ((u >> 16) & 1u)) >> 16;
    return (unsigned short)r;
}
__device__ __forceinline__ float bf2f(unsigned int us) {
    return __uint_as_float(us << 16);
}

// ---------------- CSR build ----------------

__global__ void count_k(const int* __restrict__ dst, int* __restrict__ counts, int E) {
    int e = blockIdx.x * blockDim.x + threadIdx.x;
    if (e < E) atomicAdd(&counts[dst[e]], 1);
}

__global__ __launch_bounds__(1024) void partial_k(const int* __restrict__ counts,
                                                  int* __restrict__ part, int n) {
    __shared__ int s[16];
    int tid = threadIdx.x, lane = tid & 63, wid = tid >> 6;
    int i = blockIdx.x * 1024 + tid;
    int v = (i < n) ? counts[i] : 0;
    #pragma unroll
    for (int o = 32; o > 0; o >>= 1) v += __shfl_xor(v, o);
    if (lane == 0) s[wid] = v;
    __syncthreads();
    if (tid == 0) {
        int r = 0;
        #pragma unroll
        for (int w = 0; w < 16; w++) r += s[w];
        part[blockIdx.x] = r;
    }
}

__global__ void scanpart_k(int* __restrict__ part, int nb) {  // nb <= 64, one wave
    int tid = threadIdx.x;
    int orig = (tid < nb) ? part[tid] : 0;
    int v = orig;
    #pragma unroll
    for (int o = 1; o < 64; o <<= 1) {
        int t = __shfl_up(v, o);
        if (tid >= o) v += t;
    }
    if (tid < nb) part[tid] = v - orig;   // exclusive
}

// writes offsets[i+1] AND cursor[i] = offsets[i] (so fill can atomicAdd absolute pos)
__global__ __launch_bounds__(1024) void scanwrite_k(const int* __restrict__ counts,
                                                    const int* __restrict__ part,
                                                    int* __restrict__ offsets,
                                                    int* __restrict__ cursor, int n) {
    __shared__ int s_wt[16];
    int tid = threadIdx.x, lane = tid & 63, wid = tid >> 6;
    int i = blockIdx.x * 1024 + tid;
    int v = (i < n) ? counts[i] : 0;
    int incl = v;
    #pragma unroll
    for (int o = 1; o < 64; o <<= 1) {
        int t = __shfl_up(incl, o);
        if (lane >= o) incl += t;
    }
    if (lane == 63) s_wt[wid] = incl;
    __syncthreads();
    if (tid == 0) {
        int r = 0;
        #pragma unroll
        for (int w = 0; w < 16; w++) { int t = s_wt[w]; s_wt[w] = r; r += t; }
    }
    __syncthreads();
    if (i < n) {
        int excl = part[blockIdx.x] + s_wt[wid] + incl - v;
        offsets[i + 1] = excl + v;
        cursor[i] = excl;
    }
    if (blockIdx.x == 0 && tid == 0) offsets[0] = 0;
}

__global__ void fill_csr_k(const int* __restrict__ src, const int* __restrict__ dst,
                           int* __restrict__ cursor, int* __restrict__ csr_src, int E) {
    int e = blockIdx.x * blockDim.x + threadIdx.x;
    if (e < E) {
        int pos = atomicAdd(&cursor[dst[e]], 1);
        csr_src[pos] = src[e];
    }
}

// ---------------- split-bf16 MFMA GEMM (fp32 in, bf16 out) ----------------
// C = Ahi*Bhi + Ahi*Blo + Alo*Bhi. Tile 128x64, 256 threads, 16x16x32 bf16 MFMA.

__global__ __launch_bounds__(256) void gemm_k(const float* __restrict__ A,
                                              const float* __restrict__ B,
                                              unsigned short* __restrict__ Cb,
                                              int M, int K, int Nc) {
    __shared__ __align__(16) unsigned short As_hi[128][40], As_lo[128][40];
    __shared__ __align__(16) unsigned short Bs_hi[64][40],  Bs_lo[64][40];

    const int tid = threadIdx.x;
    const int lane = tid & 63, wid = tid >> 6;
    const int row0 = blockIdx.x * 128;
    const int col0 = blockIdx.y * 64;
    const int wm = (wid & 1) * 64;
    const int wn = (wid >> 1) * 32;
    const int quad = lane >> 4, mrow = lane & 15;

    const int a_r = tid >> 1;
    const int a_k = (tid & 1) * 16;
    const int b_k = tid >> 3;
    const int b_n = (tid & 7) * 8;
    const bool a_valid = (row0 + a_r) < M;

    f32x4 acc[4][2];
    #pragma unroll
    for (int i = 0; i < 4; i++)
        #pragma unroll
        for (int j = 0; j < 2; j++) acc[i][j] = f32x4{0.f, 0.f, 0.f, 0.f};

    for (int k0 = 0; k0 < K; k0 += 32) {
        float af[16];
        if (a_valid) {
            const float* ap = &A[(size_t)(row0 + a_r) * K + k0 + a_k];
            #pragma unroll
            for (int q = 0; q < 4; q++) {
                float4 t = *(const float4*)(ap + q * 4);
                af[q * 4 + 0] = t.x; af[q * 4 + 1] = t.y;
                af[q * 4 + 2] = t.z; af[q * 4 + 3] = t.w;
            }
        } else {
            #pragma unroll
            for (int q = 0; q < 16; q++) af[q] = 0.f;
        }
        unsigned int* dh = (unsigned int*)&As_hi[a_r][a_k];
        unsigned int* dl = (unsigned int*)&As_lo[a_r][a_k];
        #pragma unroll
        for (int p = 0; p < 8; p++) {
            unsigned short h0 = f2bf(af[2 * p]), h1 = f2bf(af[2 * p + 1]);
            unsigned short l0 = f2bf(af[2 * p] - bf2f(h0));
            unsigned short l1 = f2bf(af[2 * p + 1] - bf2f(h1));
            dh[p] = (unsigned int)h0 | ((unsigned int)h1 << 16);
            dl[p] = (unsigned int)l0 | ((unsigned int)l1 << 16);
        }
        {
            const float* bp = &B[(size_t)(k0 + b_k) * Nc + col0 + b_n];
            float4 t0 = *(const float4*)(bp);
            float4 t1 = *(const float4*)(bp + 4);
            float bf[8] = {t0.x, t0.y, t0.z, t0.w, t1.x, t1.y, t1.z, t1.w};
            #pragma unroll
            for (int x = 0; x < 8; x++) {
                unsigned short h = f2bf(bf[x]);
                unsigned short l = f2bf(bf[x] - bf2f(h));
                Bs_hi[b_n + x][b_k] = h;
                Bs_lo[b_n + x][b_k] = l;
            }
        }
        __syncthreads();

        s16x8 ah[4], al[4], bh[2], bl[2];
        #pragma unroll
        for (int i = 0; i < 4; i++) {
            ah[i] = *(const s16x8*)&As_hi[wm + 16 * i + mrow][quad * 8];
            al[i] = *(const s16x8*)&As_lo[wm + 16 * i + mrow][quad * 8];
        }
        #pragma unroll
        for (int j = 0; j < 2; j++) {
            bh[j] = *(const s16x8*)&Bs_hi[wn + 16 * j + mrow][quad * 8];
            bl[j] = *(const s16x8*)&Bs_lo[wn + 16 * j + mrow][quad * 8];
        }
        #pragma unroll
        for (int i = 0; i < 4; i++)
            #pragma unroll
            for (int j = 0; j < 2; j++) {
                acc[i][j] = __builtin_amdgcn_mfma_f32_16x16x32_bf16(ah[i], bh[j], acc[i][j], 0, 0, 0);
                acc[i][j] = __builtin_amdgcn_mfma_f32_16x16x32_bf16(ah[i], bl[j], acc[i][j], 0, 0, 0);
                acc[i][j] = __builtin_amdgcn_mfma_f32_16x16x32_bf16(al[i], bh[j], acc[i][j], 0, 0, 0);
            }
        __syncthreads();
    }

    #pragma unroll
    for (int i = 0; i < 4; i++) {
        #pragma unroll
        for (int j = 0; j < 2; j++) {
            int col = col0 + wn + 16 * j + mrow;
            int rbase = row0 + wm + 16 * i + quad * 4;
            #pragma unroll
            for (int r = 0; r < 4; r++) {
                int row = rbase + r;
                if (row < M) Cb[(size_t)row * Nc + col] = f2bf(acc[i][j][r]);
            }
        }
    }
}

// ---------------- el/er from bf16 ft ----------------

template <int H, int D>
__global__ __launch_bounds__(256) void eler_k(const unsigned short* __restrict__ ft,
                                              const float* __restrict__ attn_l,
                                              const float* __restrict__ attn_r,
                                              float* __restrict__ el,
                                              float* __restrict__ er, int n_nodes) {
    constexpr int HD = H * D;
    constexpr int CPL = HD / 64;
    constexpr int G = 64 / H;
    __shared__ float s_al[HD], s_ar[HD];
    const int tid = threadIdx.x;
    for (int i = tid; i < HD; i += 256) { s_al[i] = attn_l[i]; s_ar[i] = attn_r[i]; }
    __syncthreads();
    const int lane = tid & 63, wid = tid >> 6;
    const int n = blockIdx.x * 4 + wid;
    if (n >= n_nodes) return;
    const int c0 = lane * CPL;
    const int head = c0 / D;
    float f[CPL];
    if constexpr (CPL == 4) {
        uint2 u = ((const uint2*)ft)[(size_t)n * (HD / 4) + lane];
        f[0] = bf2f(u.x & 0xffff); f[1] = bf2f(u.x >> 16);
        f[2] = bf2f(u.y & 0xffff); f[3] = bf2f(u.y >> 16);
    } else {
        unsigned int u = ((const unsigned int*)ft)[(size_t)n * (HD / 2) + lane];
        f[0] = bf2f(u & 0xffff); f[1] = bf2f(u >> 16);
    }
    float vl = 0.f, vr = 0.f;
    #pragma unroll
    for (int t = 0; t < CPL; t++) {
        vl = fmaf(f[t], s_al[c0 + t], vl);
        vr = fmaf(f[t], s_ar[c0 + t], vr);
    }
    #pragma unroll
    for (int o = G / 2; o > 0; o >>= 1) {
        vl += __shfl_xor(vl, o);
        vr += __shfl_xor(vr, o);
    }
    if ((lane & (G - 1)) == 0) {
        el[n * H + head] = vl;
        er[n * H + head] = vr;
    }
}

// ---------------- fused edge-softmax + gather-aggregate ----------------
// one WAVE per node (4 waves per block, independent, no __syncthreads).
// lane owns CPL consecutive channels; per-wave LDS slices for (src, a).

template <int H>
__device__ __forceinline__ void edge_e(const float* __restrict__ el, int sv,
                                       const float* ern, float* e) {
    if constexpr (H == 4) {
        float4 e4 = ((const float4*)el)[sv];
        float tmp[4] = {e4.x, e4.y, e4.z, e4.w};
        #pragma unroll
        for (int h = 0; h < 4; h++) {
            float t = tmp[h] + ern[h];
            e[h] = t > 0.f ? t : NEG_SLOPE * t;
        }
    } else {
        float t = el[sv] + ern[0];
        e[0] = t > 0.f ? t : NEG_SLOPE * t;
    }
}

template <int H, int CPL>
__device__ __forceinline__ void gather_edges(const unsigned short* __restrict__ ft,
                                             const int* s_src_w, const float* s_a_w,
                                             int cnt, int lane, int h_of, float* acc) {
    int i = 0;
    if constexpr (CPL == 4) {
        const uint2* fp = ((const uint2*)ft) + lane;   // row stride 64 uint2
        for (; i + 8 <= cnt; i += 8) {
            int ss[8]; float ww[8]; uint2 uu[8];
            #pragma unroll
            for (int u = 0; u < 8; u++) { ss[u] = s_src_w[i + u]; ww[u] = s_a_w[(i + u) * H + h_of]; }
            #pragma unroll
            for (int u = 0; u < 8; u++) uu[u] = fp[(size_t)ss[u] * 64];
            #pragma unroll
            for (int u = 0; u < 8; u++) {
                acc[0] = fmaf(ww[u], bf2f(uu[u].x & 0xffff), acc[0]);
                acc[1] = fmaf(ww[u], bf2f(uu[u].x >> 16), acc[1]);
                acc[2] = fmaf(ww[u], bf2f(uu[u].y & 0xffff), acc[2]);
                acc[3] = fmaf(ww[u], bf2f(uu[u].y >> 16), acc[3]);
            }
        }
        for (; i < cnt; i++) {
            float w = s_a_w[i * H + h_of];
            uint2 u = fp[(size_t)s_src_w[i] * 64];
            acc[0] = fmaf(w, bf2f(u.x & 0xffff), acc[0]);
            acc[1] = fmaf(w, bf2f(u.x >> 16), acc[1]);
            acc[2] = fmaf(w, bf2f(u.y & 0xffff), acc[2]);
            acc[3] = fmaf(w, bf2f(u.y >> 16), acc[3]);
        }
    } else {
        const unsigned int* fp = ((const unsigned int*)ft) + lane;   // row stride 64 uint
        for (; i + 8 <= cnt; i += 8) {
            int ss[8]; float ww[8]; unsigned int uu[8];
            #pragma unroll
            for (int u = 0; u < 8; u++) { ss[u] = s_src_w[i + u]; ww[u] = s_a_w[(i + u) * H + h_of]; }
            #pragma unroll
            for (int u = 0; u < 8; u++) uu[u] = fp[(size_t)ss[u] * 64];
            #pragma unroll
            for (int u = 0; u < 8; u++) {
                acc[0] = fmaf(ww[u], bf2f(uu[u] & 0xffff), acc[0]);
                acc[1] = fmaf(ww[u], bf2f(uu[u] >> 16), acc[1]);
            }
        }
        for (; i < cnt; i++) {
            float w = s_a_w[i * H + h_of];
            unsigned int u = fp[(size_t)s_src_w[i] * 64];
            acc[0] = fmaf(w, bf2f(u & 0xffff), acc[0]);
            acc[1] = fmaf(w, bf2f(u >> 16), acc[1]);
        }
    }
}

template <int H, int D, bool RELU>
__global__ __launch_bounds__(256) void fagg_k(const unsigned short* __restrict__ ft,
                                              const float* __restrict__ el,
                                              const float* __restrict__ er,
                                              const int* __restrict__ offsets,
                                              const int* __restrict__ csr_src,
                                              const float* __restrict__ bias,
                                              float* __restrict__ out, int n_nodes) {
    constexpr int HD = H * D;
    constexpr int CPL = HD / 64;   // 4 (layer1) or 2 (layer2)
    const int lane = threadIdx.x & 63;
    const int w = threadIdx.x >> 6;
    const int n = blockIdx.x * 4 + w;
    __shared__ int   s_src[4][64];
    __shared__ float s_a[4][64 * H];
    if (n >= n_nodes) return;
    const int off = offsets[n];
    const int deg = offsets[n + 1] - off;
    const int c0 = lane * CPL;
    const int h_of = c0 / D;   // wave-varying but head-group-uniform

    float ern[H];
    #pragma unroll
    for (int h = 0; h < H; h++) ern[h] = er[n * H + h];

    float acc[CPL];
    #pragma unroll
    for (int t = 0; t < CPL; t++) acc[t] = 0.f;

    const int* s_src_w = s_src[w];
    const float* s_a_w = s_a[w];

    if (deg > 0 && deg <= 64) {
        // ---- fast path: edges live in registers ----
        const bool act = lane < deg;
        int sv = 0;
        float ev[H];
        #pragma unroll
        for (int h = 0; h < H; h++) ev[h] = -1e30f;
        if (act) {
            sv = csr_src[off + lane];
            edge_e<H>(el, sv, ern, ev);
        }
        float m[H];
        #pragma unroll
        for (int h = 0; h < H; h++) m[h] = ev[h];
        #pragma unroll
        for (int h = 0; h < H; h++)
            for (int o = 32; o > 0; o >>= 1) m[h] = fmaxf(m[h], __shfl_xor(m[h], o));
        float ex[H], sm[H];
        #pragma unroll
        for (int h = 0; h < H; h++) { ex[h] = act ? __expf(ev[h] - m[h]) : 0.f; sm[h] = ex[h]; }
        #pragma unroll
        for (int h = 0; h < H; h++)
            for (int o = 32; o > 0; o >>= 1) sm[h] += __shfl_xor(sm[h], o);
        if (act) {
            s_src[w][lane] = sv;
            #pragma unroll
            for (int h = 0; h < H; h++)
                s_a[w][lane * H + h] = ex[h] * (sm[h] > 0.f ? 1.f / sm[h] : 0.f);
        }
        // same-wave LDS write->read: in-order DS pipe + compiler lgkmcnt, no barrier
        gather_edges<H, CPL>(ft, s_src_w, s_a_w, deg, lane, h_of, acc);
    } else if (deg > 64) {
        // ---- rare slow path: chunked ----
        float m[H];
        #pragma unroll
        for (int h = 0; h < H; h++) m[h] = -1e30f;
        for (int i = lane; i < deg; i += 64) {
            float e[H];
            edge_e<H>(el, csr_src[off + i], ern, e);
            #pragma unroll
            for (int h = 0; h < H; h++) m[h] = fmaxf(m[h], e[h]);
        }
        #pragma unroll
        for (int h = 0; h < H; h++)
            for (int o = 32; o > 0; o >>= 1) m[h] = fmaxf(m[h], __shfl_xor(m[h], o));
        float sm[H];
        #pragma unroll
        for (int h = 0; h < H; h++) sm[h] = 0.f;
        for (int i = lane; i < deg; i += 64) {
            float e[H];
            edge_e<H>(el, csr_src[off + i], ern, e);
            #pragma unroll
            for (int h = 0; h < H; h++) sm[h] += __expf(e[h] - m[h]);
        }
        #pragma unroll
        for (int h = 0; h < H; h++)
            for (int o = 32; o > 0; o >>= 1) sm[h] += __shfl_xor(sm[h], o);
        float inv[H];
        #pragma unroll
        for (int h = 0; h < H; h++) inv[h] = (sm[h] > 0.f) ? (1.f / sm[h]) : 0.f;
        for (int base = 0; base < deg; base += 64) {
            int cnt = min(64, deg - base);
            if (lane < cnt) {
                int sv = csr_src[off + base + lane];
                float e[H];
                edge_e<H>(el, sv, ern, e);
                s_src[w][lane] = sv;
                #pragma unroll
                for (int h = 0; h < H; h++)
                    s_a[w][lane * H + h] = __expf(e[h] - m[h]) * inv[h];
            }
            gather_edges<H, CPL>(ft, s_src_w, s_a_w, cnt, lane, h_of, acc);
        }
    }

    // epilogue: bias (+relu), vectorized store
    if constexpr (CPL == 4) {
        float4 b4 = ((const float4*)bias)[lane];
        float v0 = acc[0] + b4.x, v1 = acc[1] + b4.y, v2 = acc[2] + b4.z, v3 = acc[3] + b4.w;
        if (RELU) { v0 = fmaxf(v0, 0.f); v1 = fmaxf(v1, 0.f); v2 = fmaxf(v2, 0.f); v3 = fmaxf(v3, 0.f); }
        ((float4*)out)[(size_t)n * 64 + lane] = float4{v0, v1, v2, v3};
    } else {
        float2 b2 = ((const float2*)bias)[lane];
        float v0 = acc[0] + b2.x, v1 = acc[1] + b2.y;
        if (RELU) { v0 = fmaxf(v0, 0.f); v1 = fmaxf(v1, 0.f); }
        ((float2*)out)[(size_t)n * 64 + lane] = float2{v0, v1};
    }
}

// ---------------- launch ----------------

extern "C" void kernel_launch(void* const* d_in, const int* in_sizes, int n_in,
                              void* d_out, int out_size, void* d_ws, size_t ws_size,
                              hipStream_t stream) {
    const float* feat    = (const float*)d_in[0];
    const int*   src     = (const int*)d_in[1];
    const int*   dst     = (const int*)d_in[2];
    const float* W1      = (const float*)d_in[3];
    const float* attn_l1 = (const float*)d_in[4];
    const float* attn_r1 = (const float*)d_in[5];
    const float* bias1   = (const float*)d_in[6];
    const float* W2      = (const float*)d_in[7];
    const float* attn_l2 = (const float*)d_in[8];
    const float* attn_r2 = (const float*)d_in[9];
    const float* bias2   = (const float*)d_in[10];
    float* out = (float*)d_out;

    const int N = in_sizes[0] / 256;   // 50000
    const int E = in_sizes[1];         // 800000
    const int NB = (N + 1023) / 1024;  // 49 (<= 64)

    char* ws = (char*)d_ws;
    size_t o = 0;
    auto alloc = [&](size_t bytes) -> void* {
        void* p = ws + o;
        o = (o + bytes + 255) & ~(size_t)255;
        return p;
    };
    int* counts  = (int*)alloc((size_t)N * 4);
    int* cursor  = (int*)alloc((size_t)N * 4);
    int* offsets = (int*)alloc((size_t)(N + 1) * 4);
    int* part    = (int*)alloc(64 * 4);
    int* csr_src = (int*)alloc((size_t)E * 4);
    float* el1 = (float*)alloc((size_t)N * 4 * 4);
    float* er1 = (float*)alloc((size_t)N * 4 * 4);
    float* el2 = (float*)alloc((size_t)N * 4);
    float* er2 = (float*)alloc((size_t)N * 4);
    unsigned short* ft1b = (unsigned short*)alloc((size_t)N * 256 * 2);
    float* h1 = (float*)alloc((size_t)N * 256 * 4);
    unsigned short* ft2b = ft1b;   // ft1b dead after layer-1 aggregation

    // CSR build
    hipMemsetAsync(counts, 0, (size_t)N * 4, stream);
    count_k<<<(E + 255) / 256, 256, 0, stream>>>(dst, counts, E);
    partial_k<<<NB, 1024, 0, stream>>>(counts, part, N);
    scanpart_k<<<1, 64, 0, stream>>>(part, NB);
    scanwrite_k<<<NB, 1024, 0, stream>>>(counts, part, offsets, cursor, N);
    fill_csr_k<<<(E + 255) / 256, 256, 0, stream>>>(src, dst, cursor, csr_src, E);

    // layer 1: H=4, D=64
    gemm_k<<<dim3((N + 127) / 128, 256 / 64), 256, 0, stream>>>(feat, W1, ft1b, N, 256, 256);
    eler_k<4, 64><<<(N + 3) / 4, 256, 0, stream>>>(ft1b, attn_l1, attn_r1, el1, er1, N);
    fagg_k<4, 64, true><<<(N + 3) / 4, 256, 0, stream>>>(ft1b, el1, er1, offsets, csr_src, bias1, h1, N);

    // layer 2: H=1, D=128
    gemm_k<<<dim3((N + 127) / 128, 128 / 64), 256, 0, stream>>>(h1, W2, ft2b, N, 256, 128);
    eler_k<1, 128><<<(N + 3) / 4, 256, 0, stream>>>(ft2b, attn_l2, attn_r2, el2, er2, N);
    fagg_k<1, 128, false><<<(N + 3) / 4, 256, 0, stream>>>(ft2b, el2, er2, offsets, csr_src, bias2, out, N);
}

// Round 5
// 401.159 us; speedup vs baseline: 1.6011x; 1.0036x over previous
//
#include <hip/hip_runtime.h>
#include <hip/hip_bf16.h>

#define NEG_SLOPE 0.2f

typedef short s16x8 __attribute__((ext_vector_type(8)));
typedef float f32x4 __attribute__((ext_vector_type(4)));

__device__ __forceinline__ unsigned short f2bf(float f) {
    unsigned int u = __float_as_uint(f);
    unsigned int r = (u + 0x7fffu + ((u >> 16) & 1u)) >> 16;
    return (unsigned short)r;
}
__device__ __forceinline__ float bf2f(unsigned int us) {
    return __uint_as_float(us << 16);
}

// ---------------- count (+ fused wl precompute in block 0) ----------------
// wl1[k*8+h] = sum_d W1[k,h*64+d]*al1[h,d]; wl1[k*8+4+h] = same with ar1.
// wl2[k*2+0/1] = sum_d W2[k,d]*{al2,ar2}[d].

__global__ void count_wl_k(const int* __restrict__ dst, int* __restrict__ counts, int E,
                           const float* __restrict__ W1, const float* __restrict__ al1,
                           const float* __restrict__ ar1,
                           const float* __restrict__ W2, const float* __restrict__ al2,
                           const float* __restrict__ ar2,
                           float* __restrict__ wl1, float* __restrict__ wl2) {
    if (blockIdx.x == 0) {   // block-uniform branch
        int k = threadIdx.x; // 256
        #pragma unroll
        for (int h = 0; h < 4; h++) {
            float sl = 0.f, sr = 0.f;
            #pragma unroll 8
            for (int d = 0; d < 64; d++) {
                float wv = W1[k * 256 + h * 64 + d];
                sl = fmaf(wv, al1[h * 64 + d], sl);
                sr = fmaf(wv, ar1[h * 64 + d], sr);
            }
            wl1[k * 8 + h] = sl;
            wl1[k * 8 + 4 + h] = sr;
        }
        float sl = 0.f, sr = 0.f;
        #pragma unroll 8
        for (int d = 0; d < 128; d++) {
            float wv = W2[k * 128 + d];
            sl = fmaf(wv, al2[d], sl);
            sr = fmaf(wv, ar2[d], sr);
        }
        wl2[k * 2 + 0] = sl;
        wl2[k * 2 + 1] = sr;
        return;
    }
    int e = (blockIdx.x - 1) * 256 + threadIdx.x;
    if (e < E) atomicAdd(&counts[dst[e]], 1);
}

// ---------------- single-dispatch scan (publish-then-wait lookback) ----------
// 49 blocks x 1024 threads; flags[] zero-initialized; block b publishes
// (block_sum+1) to flags[b], then wave 0 spin-reads flags[0..b-1].
// 49 blocks << residency capacity (512 blocks of 1024) -> no deadlock.

__global__ __launch_bounds__(1024) void scan_k(const int* __restrict__ counts,
                                               int* __restrict__ flags,
                                               int* __restrict__ offsets,
                                               int* __restrict__ cursor, int n) {
    __shared__ int s_wt[16];
    __shared__ int s_base;
    const int tid = threadIdx.x, lane = tid & 63, wid = tid >> 6;
    const int bid = blockIdx.x;
    const int i = bid * 1024 + tid;
    int v = (i < n) ? counts[i] : 0;
    int incl = v;
    #pragma unroll
    for (int o = 1; o < 64; o <<= 1) {
        int t = __shfl_up(incl, o);
        if (lane >= o) incl += t;
    }
    if (lane == 63) s_wt[wid] = incl;
    __syncthreads();
    if (tid == 0) {
        int r = 0;
        #pragma unroll
        for (int w = 0; w < 16; w++) { int t = s_wt[w]; s_wt[w] = r; r += t; }
        atomicExch(&flags[bid], r + 1);   // publish block total (device scope)
        s_base = 0;
    }
    __syncthreads();
    if (wid == 0) {
        int contrib = 0;
        if (lane < bid) {
            int f;
            while ((f = atomicAdd(&flags[lane], 0)) == 0) {}
            contrib = f - 1;
        }
        #pragma unroll
        for (int o = 32; o > 0; o >>= 1) contrib += __shfl_xor(contrib, o);
        if (lane == 0) s_base = contrib;
    }
    __syncthreads();
    if (i < n) {
        int excl = s_base + s_wt[wid] + (incl - v);
        offsets[i + 1] = excl + v;
        cursor[i] = excl;
    }
    if (bid == 0 && tid == 0) offsets[0] = 0;
}

__global__ void fill_csr_k(const int* __restrict__ src, const int* __restrict__ dst,
                           int* __restrict__ cursor, int* __restrict__ csr_src, int E) {
    int e = blockIdx.x * blockDim.x + threadIdx.x;
    if (e < E) {
        int pos = atomicAdd(&cursor[dst[e]], 1);
        csr_src[pos] = src[e];
    }
}

// ---------------- split-bf16 MFMA GEMM + fused el/er epilogue ----------------
// MODE 1 (layer1, H=4): blockIdx.y = head; computes el/er[row*4+head].
// MODE 2 (layer2, H=1): blockIdx.y==0 -> el, ==1 -> er.
// K must equal 256 (s_wl sizing). C output bf16.

template <int MODE>
__global__ __launch_bounds__(256) void gemm_k(const float* __restrict__ A,
                                              const float* __restrict__ B,
                                              unsigned short* __restrict__ Cb,
                                              int M, int K, int Nc,
                                              const float* __restrict__ wl,
                                              float* __restrict__ el,
                                              float* __restrict__ er) {
    __shared__ __align__(16) unsigned short As_hi[128][40], As_lo[128][40];
    __shared__ __align__(16) unsigned short Bs_hi[64][40],  Bs_lo[64][40];
    __shared__ float s_wla[256], s_wlb[256];
    __shared__ float s_red[128][2];

    const int tid = threadIdx.x;
    const int lane = tid & 63, wid = tid >> 6;
    const int row0 = blockIdx.x * 128;
    const int by = blockIdx.y;
    const int col0 = by * 64;
    const int wm = (wid & 1) * 64;
    const int wn = (wid >> 1) * 32;
    const int quad = lane >> 4, mrow = lane & 15;

    const int a_r = tid >> 1;
    const int a_k = (tid & 1) * 16;
    const int b_k = tid >> 3;
    const int b_n = (tid & 7) * 8;
    const bool a_valid = (row0 + a_r) < M;

    if (MODE == 1) { s_wla[tid] = wl[tid * 8 + by]; s_wlb[tid] = wl[tid * 8 + 4 + by]; }
    else           { s_wla[tid] = wl[tid * 2 + by]; }
    __syncthreads();

    f32x4 acc[4][2];
    #pragma unroll
    for (int i = 0; i < 4; i++)
        #pragma unroll
        for (int j = 0; j < 2; j++) acc[i][j] = f32x4{0.f, 0.f, 0.f, 0.f};
    float pa = 0.f, pb = 0.f;

    for (int k0 = 0; k0 < K; k0 += 32) {
        float af[16];
        if (a_valid) {
            const float* ap = &A[(size_t)(row0 + a_r) * K + k0 + a_k];
            #pragma unroll
            for (int q = 0; q < 4; q++) {
                float4 t = *(const float4*)(ap + q * 4);
                af[q * 4 + 0] = t.x; af[q * 4 + 1] = t.y;
                af[q * 4 + 2] = t.z; af[q * 4 + 3] = t.w;
            }
        } else {
            #pragma unroll
            for (int q = 0; q < 16; q++) af[q] = 0.f;
        }
        // fused el/er partials (fp32, exact path)
        #pragma unroll
        for (int p = 0; p < 16; p++) {
            pa = fmaf(af[p], s_wla[k0 + a_k + p], pa);
            if (MODE == 1) pb = fmaf(af[p], s_wlb[k0 + a_k + p], pb);
        }
        unsigned int* dh = (unsigned int*)&As_hi[a_r][a_k];
        unsigned int* dl = (unsigned int*)&As_lo[a_r][a_k];
        #pragma unroll
        for (int p = 0; p < 8; p++) {
            unsigned short h0 = f2bf(af[2 * p]), h1 = f2bf(af[2 * p + 1]);
            unsigned short l0 = f2bf(af[2 * p] - bf2f(h0));
            unsigned short l1 = f2bf(af[2 * p + 1] - bf2f(h1));
            dh[p] = (unsigned int)h0 | ((unsigned int)h1 << 16);
            dl[p] = (unsigned int)l0 | ((unsigned int)l1 << 16);
        }
        {
            const float* bp = &B[(size_t)(k0 + b_k) * Nc + col0 + b_n];
            float4 t0 = *(const float4*)(bp);
            float4 t1 = *(const float4*)(bp + 4);
            float bf[8] = {t0.x, t0.y, t0.z, t0.w, t1.x, t1.y, t1.z, t1.w};
            #pragma unroll
            for (int x = 0; x < 8; x++) {
                unsigned short h = f2bf(bf[x]);
                unsigned short l = f2bf(bf[x] - bf2f(h));
                Bs_hi[b_n + x][b_k] = h;
                Bs_lo[b_n + x][b_k] = l;
            }
        }
        __syncthreads();

        s16x8 ah[4], al4[4], bh[2], bl[2];
        #pragma unroll
        for (int i = 0; i < 4; i++) {
            ah[i]  = *(const s16x8*)&As_hi[wm + 16 * i + mrow][quad * 8];
            al4[i] = *(const s16x8*)&As_lo[wm + 16 * i + mrow][quad * 8];
        }
        #pragma unroll
        for (int j = 0; j < 2; j++) {
            bh[j] = *(const s16x8*)&Bs_hi[wn + 16 * j + mrow][quad * 8];
            bl[j] = *(const s16x8*)&Bs_lo[wn + 16 * j + mrow][quad * 8];
        }
        #pragma unroll
        for (int i = 0; i < 4; i++)
            #pragma unroll
            for (int j = 0; j < 2; j++) {
                acc[i][j] = __builtin_amdgcn_mfma_f32_16x16x32_bf16(ah[i],  bh[j], acc[i][j], 0, 0, 0);
                acc[i][j] = __builtin_amdgcn_mfma_f32_16x16x32_bf16(ah[i],  bl[j], acc[i][j], 0, 0, 0);
                acc[i][j] = __builtin_amdgcn_mfma_f32_16x16x32_bf16(al4[i], bh[j], acc[i][j], 0, 0, 0);
            }
        __syncthreads();
    }

    // el/er pair-reduce (threads a_k==0/16 share row a_r)
    if (a_k == 16) { s_red[a_r][0] = pa; if (MODE == 1) s_red[a_r][1] = pb; }
    __syncthreads();
    if (a_k == 0 && a_valid) {
        float ra = pa + s_red[a_r][0];
        if (MODE == 1) {
            float rb = pb + s_red[a_r][1];
            el[(row0 + a_r) * 4 + by] = ra;
            er[(row0 + a_r) * 4 + by] = rb;
        } else {
            (by == 0 ? el : er)[row0 + a_r] = ra;
        }
    }

    #pragma unroll
    for (int i = 0; i < 4; i++) {
        #pragma unroll
        for (int j = 0; j < 2; j++) {
            int col = col0 + wn + 16 * j + mrow;
            int rbase = row0 + wm + 16 * i + quad * 4;
            #pragma unroll
            for (int r = 0; r < 4; r++) {
                int row = rbase + r;
                if (row < M) Cb[(size_t)row * Nc + col] = f2bf(acc[i][j][r]);
            }
        }
    }
}

// ---------------- fused edge-softmax + gather-aggregate ----------------

template <int H>
__device__ __forceinline__ void edge_e(const float* __restrict__ el, int sv,
                                       const float* ern, float* e) {
    if constexpr (H == 4) {
        float4 e4 = ((const float4*)el)[sv];
        float tmp[4] = {e4.x, e4.y, e4.z, e4.w};
        #pragma unroll
        for (int h = 0; h < 4; h++) {
            float t = tmp[h] + ern[h];
            e[h] = t > 0.f ? t : NEG_SLOPE * t;
        }
    } else {
        float t = el[sv] + ern[0];
        e[0] = t > 0.f ? t : NEG_SLOPE * t;
    }
}

template <int H, int CPL>
__device__ __forceinline__ void gather_edges(const unsigned short* __restrict__ ft,
                                             const int* s_src_w, const float* s_a_w,
                                             int i0, int cnt, int lane, int h_of,
                                             float* acc) {
    int i = i0;
    if constexpr (CPL == 4) {
        const uint2* fp = ((const uint2*)ft) + lane;
        for (; i + 8 <= cnt; i += 8) {
            int ss[8]; float ww[8]; uint2 uu[8];
            #pragma unroll
            for (int u = 0; u < 8; u++) ss[u] = s_src_w[i + u];
            #pragma unroll
            for (int u = 0; u < 8; u++) uu[u] = fp[(size_t)ss[u] * 64];
            #pragma unroll
            for (int u = 0; u < 8; u++) ww[u] = s_a_w[(i + u) * H + h_of];
            #pragma unroll
            for (int u = 0; u < 8; u++) {
                acc[0] = fmaf(ww[u], bf2f(uu[u].x & 0xffff), acc[0]);
                acc[1] = fmaf(ww[u], bf2f(uu[u].x >> 16), acc[1]);
                acc[2] = fmaf(ww[u], bf2f(uu[u].y & 0xffff), acc[2]);
                acc[3] = fmaf(ww[u], bf2f(uu[u].y >> 16), acc[3]);
            }
        }
        for (; i < cnt; i++) {
            float w = s_a_w[i * H + h_of];
            uint2 u = fp[(size_t)s_src_w[i] * 64];
            acc[0] = fmaf(w, bf2f(u.x & 0xffff), acc[0]);
            acc[1] = fmaf(w, bf2f(u.x >> 16), acc[1]);
            acc[2] = fmaf(w, bf2f(u.y & 0xffff), acc[2]);
            acc[3] = fmaf(w, bf2f(u.y >> 16), acc[3]);
        }
    } else {
        const unsigned int* fp = ((const unsigned int*)ft) + lane;
        for (; i + 8 <= cnt; i += 8) {
            int ss[8]; float ww[8]; unsigned int uu[8];
            #pragma unroll
            for (int u = 0; u < 8; u++) ss[u] = s_src_w[i + u];
            #pragma unroll
            for (int u = 0; u < 8; u++) uu[u] = fp[(size_t)ss[u] * 64];
            #pragma unroll
            for (int u = 0; u < 8; u++) ww[u] = s_a_w[(i + u) * H + h_of];
            #pragma unroll
            for (int u = 0; u < 8; u++) {
                acc[0] = fmaf(ww[u], bf2f(uu[u] & 0xffff), acc[0]);
                acc[1] = fmaf(ww[u], bf2f(uu[u] >> 16), acc[1]);
            }
        }
        for (; i < cnt; i++) {
            float w = s_a_w[i * H + h_of];
            unsigned int u = fp[(size_t)s_src_w[i] * 64];
            acc[0] = fmaf(w, bf2f(u & 0xffff), acc[0]);
            acc[1] = fmaf(w, bf2f(u >> 16), acc[1]);
        }
    }
}

template <int H, int D, bool RELU>
__global__ __launch_bounds__(256) void fagg_k(const unsigned short* __restrict__ ft,
                                              const float* __restrict__ el,
                                              const float* __restrict__ er,
                                              const int* __restrict__ offsets,
                                              const int* __restrict__ csr_src,
                                              const float* __restrict__ bias,
                                              float* __restrict__ out, int n_nodes) {
    constexpr int HD = H * D;
    constexpr int CPL = HD / 64;   // 4 (layer1) or 2 (layer2)
    const int lane = threadIdx.x & 63;
    const int w = threadIdx.x >> 6;
    const int n = blockIdx.x * 4 + w;
    __shared__ int   s_src[4][64];
    __shared__ float s_a[4][64 * H];
    if (n >= n_nodes) return;
    const int off = offsets[n];
    const int deg = offsets[n + 1] - off;
    const int c0 = lane * CPL;
    const int h_of = c0 / D;

    float ern[H];
    #pragma unroll
    for (int h = 0; h < H; h++) ern[h] = er[n * H + h];

    float acc[CPL];
    #pragma unroll
    for (int t = 0; t < CPL; t++) acc[t] = 0.f;

    const int* s_src_w = s_src[w];
    const float* s_a_w = s_a[w];

    if (deg > 0 && deg <= 64) {
        // ---- fast path ----
        const bool act = lane < deg;
        int sv = 0;
        if (act) { sv = csr_src[off + lane]; s_src[w][lane] = sv; }
        // issue el gather first (softmax needs it)
        float4 elv = float4{0.f, 0.f, 0.f, 0.f};
        float el1v = 0.f;
        if constexpr (H == 4) { if (act) elv = ((const float4*)el)[sv]; }
        else                  { if (act) el1v = el[sv]; }
        // prefetch first 8 ft rows (addresses via shfl, independent of softmax)
        const int P = deg < 8 ? deg : 8;
        uint2 pre4[8]; unsigned int pre2[8];
        if constexpr (CPL == 4) {
            const uint2* fp = ((const uint2*)ft) + lane;
            #pragma unroll
            for (int u = 0; u < 8; u++)
                if (u < P) { int su = __shfl(sv, u); pre4[u] = fp[(size_t)su * 64]; }
        } else {
            const unsigned int* fp = ((const unsigned int*)ft) + lane;
            #pragma unroll
            for (int u = 0; u < 8; u++)
                if (u < P) { int su = __shfl(sv, u); pre2[u] = fp[(size_t)su * 64]; }
        }
        // softmax
        float ev[H];
        if constexpr (H == 4) {
            float tmp[4] = {elv.x, elv.y, elv.z, elv.w};
            #pragma unroll
            for (int h = 0; h < 4; h++) {
                float t = tmp[h] + ern[h];
                t = t > 0.f ? t : NEG_SLOPE * t;
                ev[h] = act ? t : -1e30f;
            }
        } else {
            float t = el1v + ern[0];
            t = t > 0.f ? t : NEG_SLOPE * t;
            ev[0] = act ? t : -1e30f;
        }
        float m[H];
        #pragma unroll
        for (int h = 0; h < H; h++) m[h] = ev[h];
        #pragma unroll
        for (int h = 0; h < H; h++)
            for (int o = 32; o > 0; o >>= 1) m[h] = fmaxf(m[h], __shfl_xor(m[h], o));
        float ex[H], sm[H];
        #pragma unroll
        for (int h = 0; h < H; h++) { ex[h] = act ? __expf(ev[h] - m[h]) : 0.f; sm[h] = ex[h]; }
        #pragma unroll
        for (int h = 0; h < H; h++)
            for (int o = 32; o > 0; o >>= 1) sm[h] += __shfl_xor(sm[h], o);
        if (act) {
            #pragma unroll
            for (int h = 0; h < H; h++)
                s_a[w][lane * H + h] = ex[h] * (sm[h] > 0.f ? 1.f / sm[h] : 0.f);
        }
        // consume prefetched rows (same-wave LDS write->read, no barrier needed)
        if constexpr (CPL == 4) {
            #pragma unroll
            for (int u = 0; u < 8; u++)
                if (u < P) {
                    float wgt = s_a_w[u * H + h_of];
                    acc[0] = fmaf(wgt, bf2f(pre4[u].x & 0xffff), acc[0]);
                    acc[1] = fmaf(wgt, bf2f(pre4[u].x >> 16), acc[1]);
                    acc[2] = fmaf(wgt, bf2f(pre4[u].y & 0xffff), acc[2]);
                    acc[3] = fmaf(wgt, bf2f(pre4[u].y >> 16), acc[3]);
                }
        } else {
            #pragma unroll
            for (int u = 0; u < 8; u++)
                if (u < P) {
                    float wgt = s_a_w[u * H + h_of];
                    acc[0] = fmaf(wgt, bf2f(pre2[u] & 0xffff), acc[0]);
                    acc[1] = fmaf(wgt, bf2f(pre2[u] >> 16), acc[1]);
                }
        }
        gather_edges<H, CPL>(ft, s_src_w, s_a_w, P, deg, lane, h_of, acc);
    } else if (deg > 64) {
        // ---- rare slow path: chunked ----
        float m[H];
        #pragma unroll
        for (int h = 0; h < H; h++) m[h] = -1e30f;
        for (int i = lane; i < deg; i += 64) {
            float e[H];
            edge_e<H>(el, csr_src[off + i], ern, e);
            #pragma unroll
            for (int h = 0; h < H; h++) m[h] = fmaxf(m[h], e[h]);
        }
        #pragma unroll
        for (int h = 0; h < H; h++)
            for (int o = 32; o > 0; o >>= 1) m[h] = fmaxf(m[h], __shfl_xor(m[h], o));
        float sm[H];
        #pragma unroll
        for (int h = 0; h < H; h++) sm[h] = 0.f;
        for (int i = lane; i < deg; i += 64) {
            float e[H];
            edge_e<H>(el, csr_src[off + i], ern, e);
            #pragma unroll
            for (int h = 0; h < H; h++) sm[h] += __expf(e[h] - m[h]);
        }
        #pragma unroll
        for (int h = 0; h < H; h++)
            for (int o = 32; o > 0; o >>= 1) sm[h] += __shfl_xor(sm[h], o);
        float inv[H];
        #pragma unroll
        for (int h = 0; h < H; h++) inv[h] = (sm[h] > 0.f) ? (1.f / sm[h]) : 0.f;
        for (int base = 0; base < deg; base += 64) {
            int cnt = min(64, deg - base);
            if (lane < cnt) {
                int sv = csr_src[off + base + lane];
                float e[H];
                edge_e<H>(el, sv, ern, e);
                s_src[w][lane] = sv;
                #pragma unroll
                for (int h = 0; h < H; h++)
                    s_a[w][lane * H + h] = __expf(e[h] - m[h]) * inv[h];
            }
            gather_edges<H, CPL>(ft, s_src_w, s_a_w, 0, cnt, lane, h_of, acc);
        }
    }

    if constexpr (CPL == 4) {
        float4 b4 = ((const float4*)bias)[lane];
        float v0 = acc[0] + b4.x, v1 = acc[1] + b4.y, v2 = acc[2] + b4.z, v3 = acc[3] + b4.w;
        if (RELU) { v0 = fmaxf(v0, 0.f); v1 = fmaxf(v1, 0.f); v2 = fmaxf(v2, 0.f); v3 = fmaxf(v3, 0.f); }
        ((float4*)out)[(size_t)n * 64 + lane] = float4{v0, v1, v2, v3};
    } else {
        float2 b2 = ((const float2*)bias)[lane];
        float v0 = acc[0] + b2.x, v1 = acc[1] + b2.y;
        if (RELU) { v0 = fmaxf(v0, 0.f); v1 = fmaxf(v1, 0.f); }
        ((float2*)out)[(size_t)n * 64 + lane] = float2{v0, v1};
    }
}

// ---------------- launch ----------------

extern "C" void kernel_launch(void* const* d_in, const int* in_sizes, int n_in,
                              void* d_out, int out_size, void* d_ws, size_t ws_size,
                              hipStream_t stream) {
    const float* feat    = (const float*)d_in[0];
    const int*   src     = (const int*)d_in[1];
    const int*   dst     = (const int*)d_in[2];
    const float* W1      = (const float*)d_in[3];
    const float* attn_l1 = (const float*)d_in[4];
    const float* attn_r1 = (const float*)d_in[5];
    const float* bias1   = (const float*)d_in[6];
    const float* W2      = (const float*)d_in[7];
    const float* attn_l2 = (const float*)d_in[8];
    const float* attn_r2 = (const float*)d_in[9];
    const float* bias2   = (const float*)d_in[10];
    float* out = (float*)d_out;

    const int N = in_sizes[0] / 256;   // 50000
    const int E = in_sizes[1];         // 800000
    const int NB = (N + 1023) / 1024;  // 49 (<= 64 for lookback wave)

    char* ws = (char*)d_ws;
    size_t o = 0;
    auto alloc = [&](size_t bytes) -> void* {
        void* p = ws + o;
        o = (o + bytes + 255) & ~(size_t)255;
        return p;
    };
    // counts + flags contiguous -> single memset
    int* counts  = (int*)alloc((size_t)(N + 64) * 4);
    int* flags   = counts + N;
    int* cursor  = (int*)alloc((size_t)N * 4);
    int* offsets = (int*)alloc((size_t)(N + 1) * 4);
    int* csr_src = (int*)alloc((size_t)E * 4);
    float* wl1 = (float*)alloc(256 * 8 * 4);
    float* wl2 = (float*)alloc(256 * 2 * 4);
    float* el1 = (float*)alloc((size_t)N * 4 * 4);
    float* er1 = (float*)alloc((size_t)N * 4 * 4);
    float* el2 = (float*)alloc((size_t)N * 4);
    float* er2 = (float*)alloc((size_t)N * 4);
    unsigned short* ft1b = (unsigned short*)alloc((size_t)N * 256 * 2);
    float* h1 = (float*)alloc((size_t)N * 256 * 4);
    unsigned short* ft2b = ft1b;   // ft1b dead after layer-1 aggregation

    // 1. zero counts+flags
    hipMemsetAsync(counts, 0, (size_t)(N + 64) * 4, stream);
    // 2. count + wl precompute
    count_wl_k<<<1 + (E + 255) / 256, 256, 0, stream>>>(dst, counts, E,
        W1, attn_l1, attn_r1, W2, attn_l2, attn_r2, wl1, wl2);
    // 3. single-dispatch scan
    scan_k<<<NB, 1024, 0, stream>>>(counts, flags, offsets, cursor, N);
    // 4. fill CSR
    fill_csr_k<<<(E + 255) / 256, 256, 0, stream>>>(src, dst, cursor, csr_src, E);

    // 5. layer 1 GEMM (+el1/er1), 6. fused softmax+aggregate
    gemm_k<1><<<dim3((N + 127) / 128, 4), 256, 0, stream>>>(feat, W1, ft1b, N, 256, 256,
                                                            wl1, el1, er1);
    fagg_k<4, 64, true><<<(N + 3) / 4, 256, 0, stream>>>(ft1b, el1, er1, offsets, csr_src,
                                                         bias1, h1, N);

    // 7. layer 2 GEMM (+el2/er2), 8. fused softmax+aggregate
    gemm_k<2><<<dim3((N + 127) / 128, 2), 256, 0, stream>>>(h1, W2, ft2b, N, 256, 128,
                                                            wl2, el2, er2);
    fagg_k<1, 128, false><<<(N + 3) / 4, 256, 0, stream>>>(ft2b, el2, er2, offsets, csr_src,
                                                           bias2, out, N);
}

// Round 6
// 388.075 us; speedup vs baseline: 1.6551x; 1.0337x over previous
//
#include <hip/hip_runtime.h>
#include <hip/hip_bf16.h>

#define NEG_SLOPE 0.2f

typedef short s16x8 __attribute__((ext_vector_type(8)));
typedef float f32x4 __attribute__((ext_vector_type(4)));

__device__ __forceinline__ unsigned short f2bf(float f) {
    unsigned int u = __float_as_uint(f);
    unsigned int r = (u + 0x7fffu + ((u >> 16) & 1u)) >> 16;
    return (unsigned short)r;
}
__device__ __forceinline__ float bf2f(unsigned int us) {
    return __uint_as_float(us << 16);
}

// ---------------- count (+ fused wl precompute in block 0) ----------------

__global__ void count_wl_k(const int* __restrict__ dst, int* __restrict__ counts, int E,
                           const float* __restrict__ W1, const float* __restrict__ al1,
                           const float* __restrict__ ar1,
                           const float* __restrict__ W2, const float* __restrict__ al2,
                           const float* __restrict__ ar2,
                           float* __restrict__ wl1, float* __restrict__ wl2) {
    if (blockIdx.x == 0) {   // block-uniform branch
        int k = threadIdx.x; // 256
        #pragma unroll
        for (int h = 0; h < 4; h++) {
            float sl = 0.f, sr = 0.f;
            #pragma unroll 8
            for (int d = 0; d < 64; d++) {
                float wv = W1[k * 256 + h * 64 + d];
                sl = fmaf(wv, al1[h * 64 + d], sl);
                sr = fmaf(wv, ar1[h * 64 + d], sr);
            }
            wl1[k * 8 + h] = sl;
            wl1[k * 8 + 4 + h] = sr;
        }
        float sl = 0.f, sr = 0.f;
        #pragma unroll 8
        for (int d = 0; d < 128; d++) {
            float wv = W2[k * 128 + d];
            sl = fmaf(wv, al2[d], sl);
            sr = fmaf(wv, ar2[d], sr);
        }
        wl2[k * 2 + 0] = sl;
        wl2[k * 2 + 1] = sr;
        return;
    }
    int e = (blockIdx.x - 1) * 256 + threadIdx.x;
    if (e < E) atomicAdd(&counts[dst[e]], 1);
}

// ---------------- single-dispatch scan (publish-then-wait lookback) ----------

__global__ __launch_bounds__(1024) void scan_k(const int* __restrict__ counts,
                                               int* __restrict__ flags,
                                               int* __restrict__ offsets,
                                               int* __restrict__ cursor, int n) {
    __shared__ int s_wt[16];
    __shared__ int s_base;
    const int tid = threadIdx.x, lane = tid & 63, wid = tid >> 6;
    const int bid = blockIdx.x;
    const int i = bid * 1024 + tid;
    int v = (i < n) ? counts[i] : 0;
    int incl = v;
    #pragma unroll
    for (int o = 1; o < 64; o <<= 1) {
        int t = __shfl_up(incl, o);
        if (lane >= o) incl += t;
    }
    if (lane == 63) s_wt[wid] = incl;
    __syncthreads();
    if (tid == 0) {
        int r = 0;
        #pragma unroll
        for (int w = 0; w < 16; w++) { int t = s_wt[w]; s_wt[w] = r; r += t; }
        atomicExch(&flags[bid], r + 1);   // publish block total
        s_base = 0;
    }
    __syncthreads();
    if (wid == 0) {
        int contrib = 0;
        if (lane < bid) {
            int f;
            while ((f = atomicAdd(&flags[lane], 0)) == 0) {}
            contrib = f - 1;
        }
        #pragma unroll
        for (int o = 32; o > 0; o >>= 1) contrib += __shfl_xor(contrib, o);
        if (lane == 0) s_base = contrib;
    }
    __syncthreads();
    if (i < n) {
        int excl = s_base + s_wt[wid] + (incl - v);
        offsets[i + 1] = excl + v;
        cursor[i] = excl;
    }
    if (bid == 0 && tid == 0) offsets[0] = 0;
}

__global__ void fill_csr_k(const int* __restrict__ src, const int* __restrict__ dst,
                           int* __restrict__ cursor, int* __restrict__ csr_src, int E) {
    int e = blockIdx.x * blockDim.x + threadIdx.x;
    if (e < E) {
        int pos = atomicAdd(&cursor[dst[e]], 1);
        csr_src[pos] = src[e];
    }
}

// ---------------- split-bf16 MFMA GEMM + fused el/er epilogue ----------------
// grid = (by, row_blocks): by fastest so blocks sharing an A-tile are adjacent
// in dispatch order -> A read once from HBM, rest L2 hits.

template <int MODE>
__global__ __launch_bounds__(256) void gemm_k(const float* __restrict__ A,
                                              const float* __restrict__ B,
                                              unsigned short* __restrict__ Cb,
                                              int M, int K, int Nc,
                                              const float* __restrict__ wl,
                                              float* __restrict__ el,
                                              float* __restrict__ er) {
    __shared__ __align__(16) unsigned short As_hi[128][40], As_lo[128][40];
    __shared__ __align__(16) unsigned short Bs_hi[64][40],  Bs_lo[64][40];
    __shared__ float s_wla[256], s_wlb[256];
    __shared__ float s_red[128][2];

    const int tid = threadIdx.x;
    const int lane = tid & 63, wid = tid >> 6;
    const int by = blockIdx.x;                 // head / column block (fastest)
    const int row0 = blockIdx.y * 128;
    const int col0 = by * 64;
    const int wm = (wid & 1) * 64;
    const int wn = (wid >> 1) * 32;
    const int quad = lane >> 4, mrow = lane & 15;

    const int a_r = tid >> 1;
    const int a_k = (tid & 1) * 16;
    const int b_k = tid >> 3;
    const int b_n = (tid & 7) * 8;
    const bool a_valid = (row0 + a_r) < M;

    if (MODE == 1) { s_wla[tid] = wl[tid * 8 + by]; s_wlb[tid] = wl[tid * 8 + 4 + by]; }
    else           { s_wla[tid] = wl[tid * 2 + by]; }
    __syncthreads();

    f32x4 acc[4][2];
    #pragma unroll
    for (int i = 0; i < 4; i++)
        #pragma unroll
        for (int j = 0; j < 2; j++) acc[i][j] = f32x4{0.f, 0.f, 0.f, 0.f};
    float pa = 0.f, pb = 0.f;

    for (int k0 = 0; k0 < K; k0 += 32) {
        float af[16];
        if (a_valid) {
            const float* ap = &A[(size_t)(row0 + a_r) * K + k0 + a_k];
            #pragma unroll
            for (int q = 0; q < 4; q++) {
                float4 t = *(const float4*)(ap + q * 4);
                af[q * 4 + 0] = t.x; af[q * 4 + 1] = t.y;
                af[q * 4 + 2] = t.z; af[q * 4 + 3] = t.w;
            }
        } else {
            #pragma unroll
            for (int q = 0; q < 16; q++) af[q] = 0.f;
        }
        #pragma unroll
        for (int p = 0; p < 16; p++) {
            pa = fmaf(af[p], s_wla[k0 + a_k + p], pa);
            if (MODE == 1) pb = fmaf(af[p], s_wlb[k0 + a_k + p], pb);
        }
        unsigned int* dh = (unsigned int*)&As_hi[a_r][a_k];
        unsigned int* dl = (unsigned int*)&As_lo[a_r][a_k];
        #pragma unroll
        for (int p = 0; p < 8; p++) {
            unsigned short h0 = f2bf(af[2 * p]), h1 = f2bf(af[2 * p + 1]);
            unsigned short l0 = f2bf(af[2 * p] - bf2f(h0));
            unsigned short l1 = f2bf(af[2 * p + 1] - bf2f(h1));
            dh[p] = (unsigned int)h0 | ((unsigned int)h1 << 16);
            dl[p] = (unsigned int)l0 | ((unsigned int)l1 << 16);
        }
        {
            const float* bp = &B[(size_t)(k0 + b_k) * Nc + col0 + b_n];
            float4 t0 = *(const float4*)(bp);
            float4 t1 = *(const float4*)(bp + 4);
            float bf[8] = {t0.x, t0.y, t0.z, t0.w, t1.x, t1.y, t1.z, t1.w};
            #pragma unroll
            for (int x = 0; x < 8; x++) {
                unsigned short h = f2bf(bf[x]);
                unsigned short l = f2bf(bf[x] - bf2f(h));
                Bs_hi[b_n + x][b_k] = h;
                Bs_lo[b_n + x][b_k] = l;
            }
        }
        __syncthreads();

        s16x8 ah[4], al4[4], bh[2], bl[2];
        #pragma unroll
        for (int i = 0; i < 4; i++) {
            ah[i]  = *(const s16x8*)&As_hi[wm + 16 * i + mrow][quad * 8];
            al4[i] = *(const s16x8*)&As_lo[wm + 16 * i + mrow][quad * 8];
        }
        #pragma unroll
        for (int j = 0; j < 2; j++) {
            bh[j] = *(const s16x8*)&Bs_hi[wn + 16 * j + mrow][quad * 8];
            bl[j] = *(const s16x8*)&Bs_lo[wn + 16 * j + mrow][quad * 8];
        }
        #pragma unroll
        for (int i = 0; i < 4; i++)
            #pragma unroll
            for (int j = 0; j < 2; j++) {
                acc[i][j] = __builtin_amdgcn_mfma_f32_16x16x32_bf16(ah[i],  bh[j], acc[i][j], 0, 0, 0);
                acc[i][j] = __builtin_amdgcn_mfma_f32_16x16x32_bf16(ah[i],  bl[j], acc[i][j], 0, 0, 0);
                acc[i][j] = __builtin_amdgcn_mfma_f32_16x16x32_bf16(al4[i], bh[j], acc[i][j], 0, 0, 0);
            }
        __syncthreads();
    }

    if (a_k == 16) { s_red[a_r][0] = pa; if (MODE == 1) s_red[a_r][1] = pb; }
    __syncthreads();
    if (a_k == 0 && a_valid) {
        float ra = pa + s_red[a_r][0];
        if (MODE == 1) {
            float rb = pb + s_red[a_r][1];
            el[(row0 + a_r) * 4 + by] = ra;
            er[(row0 + a_r) * 4 + by] = rb;
        } else {
            (by == 0 ? el : er)[row0 + a_r] = ra;
        }
    }

    #pragma unroll
    for (int i = 0; i < 4; i++) {
        #pragma unroll
        for (int j = 0; j < 2; j++) {
            int col = col0 + wn + 16 * j + mrow;
            int rbase = row0 + wm + 16 * i + quad * 4;
            #pragma unroll
            for (int r = 0; r < 4; r++) {
                int row = rbase + r;
                if (row < M) Cb[(size_t)row * Nc + col] = f2bf(acc[i][j][r]);
            }
        }
    }
}

// ---------------- fused edge-softmax + wide-row gather-aggregate ----------------
// one WAVE per node. Each lane loads 16B (uint4 = 8 bf16 channels); LPE lanes
// cover one ft row, so one wave-load fetches EPI=64/LPE edges at once.
// Edge tails are zero-padded (weight 0, src 0) -> guard-free gather loop.

__device__ __forceinline__ void fma8(float* acc, float wgt, uint4 u) {
    acc[0] = fmaf(wgt, bf2f(u.x & 0xffff), acc[0]);
    acc[1] = fmaf(wgt, bf2f(u.x >> 16),    acc[1]);
    acc[2] = fmaf(wgt, bf2f(u.y & 0xffff), acc[2]);
    acc[3] = fmaf(wgt, bf2f(u.y >> 16),    acc[3]);
    acc[4] = fmaf(wgt, bf2f(u.z & 0xffff), acc[4]);
    acc[5] = fmaf(wgt, bf2f(u.z >> 16),    acc[5]);
    acc[6] = fmaf(wgt, bf2f(u.w & 0xffff), acc[6]);
    acc[7] = fmaf(wgt, bf2f(u.w >> 16),    acc[7]);
}

template <int H, int D, bool RELU>
__global__ __launch_bounds__(256) void fagg_k(const unsigned short* __restrict__ ft,
                                              const float* __restrict__ el,
                                              const float* __restrict__ er,
                                              const int* __restrict__ offsets,
                                              const int* __restrict__ csr_src,
                                              const float* __restrict__ bias,
                                              float* __restrict__ out, int n_nodes) {
    constexpr int HD = H * D;
    constexpr int LPE = HD / 8;    // lanes per edge-row (16B/lane): 32 (L1), 16 (L2)
    constexpr int EPI = 64 / LPE;  // edges per wave-load: 2 (L1), 4 (L2)
    const int lane = threadIdx.x & 63;
    const int w = threadIdx.x >> 6;
    const int n = blockIdx.x * 4 + w;
    __shared__ int   s_src[4][64];
    __shared__ float s_a[4][64 * H];
    if (n >= n_nodes) return;
    const int off = offsets[n];
    const int deg = offsets[n + 1] - off;
    const int lane_sub = lane & (LPE - 1);
    const int q = lane / LPE;          // which of the EPI edges this lane serves
    const int c0 = lane_sub * 8;
    const int h_of = c0 / D;

    float ern[H];
    #pragma unroll
    for (int h = 0; h < H; h++) ern[h] = er[n * H + h];

    float acc[8];
    #pragma unroll
    for (int t = 0; t < 8; t++) acc[t] = 0.f;

    const int* s_src_w = s_src[w];
    const float* s_a_w = s_a[w];
    const uint4* fp = ((const uint4*)ft) + lane_sub;

    if (deg <= 64) {
        // ---- fast path: all edges in one wave pass ----
        const bool act = lane < deg;
        int sv = act ? csr_src[off + lane] : 0;
        s_src[w][lane] = sv;
        // issue el gather (sv=0 safe for inactive lanes)
        float evr[H];
        if constexpr (H == 4) {
            float4 e4 = ((const float4*)el)[sv];
            evr[0] = e4.x; evr[1] = e4.y; evr[2] = e4.z; evr[3] = e4.w;
        } else {
            evr[0] = el[sv];
        }
        // prefetch first 4*EPI edges (addresses depend only on s_src)
        int p0, p1, p2, p3;
        {
            p0 = s_src_w[q]; p1 = s_src_w[EPI + q];
            p2 = s_src_w[2 * EPI + q]; p3 = s_src_w[3 * EPI + q];
        }
        uint4 u0 = fp[(size_t)p0 * LPE];
        uint4 u1 = fp[(size_t)p1 * LPE];
        uint4 u2 = fp[(size_t)p2 * LPE];
        uint4 u3 = fp[(size_t)p3 * LPE];
        // softmax
        float ev[H], m[H];
        #pragma unroll
        for (int h = 0; h < H; h++) {
            float t = evr[h] + ern[h];
            t = t > 0.f ? t : NEG_SLOPE * t;
            ev[h] = act ? t : -1e30f;
            m[h] = ev[h];
        }
        #pragma unroll
        for (int h = 0; h < H; h++)
            for (int o = 32; o > 0; o >>= 1) m[h] = fmaxf(m[h], __shfl_xor(m[h], o));
        float ex[H], sm[H];
        #pragma unroll
        for (int h = 0; h < H; h++) { ex[h] = act ? __expf(ev[h] - m[h]) : 0.f; sm[h] = ex[h]; }
        #pragma unroll
        for (int h = 0; h < H; h++)
            for (int o = 32; o > 0; o >>= 1) sm[h] += __shfl_xor(sm[h], o);
        #pragma unroll
        for (int h = 0; h < H; h++)
            s_a[w][lane * H + h] = ex[h] * (sm[h] > 0.f ? 1.f / sm[h] : 0.f);  // 0 for pads
        // consume prefetched (weights read from LDS; same-wave ordering via lgkmcnt)
        fma8(acc, s_a_w[(q) * H + h_of], u0);
        fma8(acc, s_a_w[(EPI + q) * H + h_of], u1);
        fma8(acc, s_a_w[(2 * EPI + q) * H + h_of], u2);
        fma8(acc, s_a_w[(3 * EPI + q) * H + h_of], u3);
        const int rc = (deg + EPI - 1) & ~(EPI - 1);
        int i = 4 * EPI;
        for (; i + 4 * EPI <= rc; i += 4 * EPI) {
            int e0 = i + q, e1 = i + EPI + q, e2 = i + 2 * EPI + q, e3 = i + 3 * EPI + q;
            int s0 = s_src_w[e0], s1 = s_src_w[e1], s2 = s_src_w[e2], s3 = s_src_w[e3];
            uint4 v0 = fp[(size_t)s0 * LPE];
            uint4 v1 = fp[(size_t)s1 * LPE];
            uint4 v2 = fp[(size_t)s2 * LPE];
            uint4 v3 = fp[(size_t)s3 * LPE];
            float w0 = s_a_w[e0 * H + h_of], w1 = s_a_w[e1 * H + h_of];
            float w2 = s_a_w[e2 * H + h_of], w3 = s_a_w[e3 * H + h_of];
            fma8(acc, w0, v0); fma8(acc, w1, v1); fma8(acc, w2, v2); fma8(acc, w3, v3);
        }
        for (; i < rc; i += EPI) {
            int e = i + q;
            int s = s_src_w[e];
            uint4 v = fp[(size_t)s * LPE];
            fma8(acc, s_a_w[e * H + h_of], v);
        }
    } else {
        // ---- rare slow path: two-pass softmax, then 64-edge chunks ----
        float m[H];
        #pragma unroll
        for (int h = 0; h < H; h++) m[h] = -1e30f;
        for (int i = lane; i < deg; i += 64) {
            int sv = csr_src[off + i];
            if constexpr (H == 4) {
                float4 e4 = ((const float4*)el)[sv];
                float tmp[4] = {e4.x, e4.y, e4.z, e4.w};
                #pragma unroll
                for (int h = 0; h < 4; h++) {
                    float t = tmp[h] + ern[h];
                    t = t > 0.f ? t : NEG_SLOPE * t;
                    m[h] = fmaxf(m[h], t);
                }
            } else {
                float t = el[sv] + ern[0];
                t = t > 0.f ? t : NEG_SLOPE * t;
                m[0] = fmaxf(m[0], t);
            }
        }
        #pragma unroll
        for (int h = 0; h < H; h++)
            for (int o = 32; o > 0; o >>= 1) m[h] = fmaxf(m[h], __shfl_xor(m[h], o));
        float sm[H];
        #pragma unroll
        for (int h = 0; h < H; h++) sm[h] = 0.f;
        for (int i = lane; i < deg; i += 64) {
            int sv = csr_src[off + i];
            if constexpr (H == 4) {
                float4 e4 = ((const float4*)el)[sv];
                float tmp[4] = {e4.x, e4.y, e4.z, e4.w};
                #pragma unroll
                for (int h = 0; h < 4; h++) {
                    float t = tmp[h] + ern[h];
                    t = t > 0.f ? t : NEG_SLOPE * t;
                    sm[h] += __expf(t - m[h]);
                }
            } else {
                float t = el[sv] + ern[0];
                t = t > 0.f ? t : NEG_SLOPE * t;
                sm[0] += __expf(t - m[0]);
            }
        }
        #pragma unroll
        for (int h = 0; h < H; h++)
            for (int o = 32; o > 0; o >>= 1) sm[h] += __shfl_xor(sm[h], o);
        float inv[H];
        #pragma unroll
        for (int h = 0; h < H; h++) inv[h] = (sm[h] > 0.f) ? (1.f / sm[h]) : 0.f;
        for (int base = 0; base < deg; base += 64) {
            const bool act2 = base + lane < deg;
            int sv = act2 ? csr_src[off + base + lane] : 0;
            s_src[w][lane] = sv;
            float exh[H];
            if constexpr (H == 4) {
                float4 e4 = ((const float4*)el)[sv];
                float tmp[4] = {e4.x, e4.y, e4.z, e4.w};
                #pragma unroll
                for (int h = 0; h < 4; h++) {
                    float t = tmp[h] + ern[h];
                    t = t > 0.f ? t : NEG_SLOPE * t;
                    exh[h] = act2 ? __expf(t - m[h]) * inv[h] : 0.f;
                }
            } else {
                float t = el[sv] + ern[0];
                t = t > 0.f ? t : NEG_SLOPE * t;
                exh[0] = act2 ? __expf(t - m[0]) * inv[0] : 0.f;
            }
            #pragma unroll
            for (int h = 0; h < H; h++) s_a[w][lane * H + h] = exh[h];
            int cnt = min(64, deg - base);
            int rc = (cnt + EPI - 1) & ~(EPI - 1);
            int i = 0;
            for (; i + 4 * EPI <= rc; i += 4 * EPI) {
                int e0 = i + q, e1 = i + EPI + q, e2 = i + 2 * EPI + q, e3 = i + 3 * EPI + q;
                int s0 = s_src_w[e0], s1 = s_src_w[e1], s2 = s_src_w[e2], s3 = s_src_w[e3];
                uint4 v0 = fp[(size_t)s0 * LPE];
                uint4 v1 = fp[(size_t)s1 * LPE];
                uint4 v2 = fp[(size_t)s2 * LPE];
                uint4 v3 = fp[(size_t)s3 * LPE];
                float w0 = s_a_w[e0 * H + h_of], w1 = s_a_w[e1 * H + h_of];
                float w2 = s_a_w[e2 * H + h_of], w3 = s_a_w[e3 * H + h_of];
                fma8(acc, w0, v0); fma8(acc, w1, v1); fma8(acc, w2, v2); fma8(acc, w3, v3);
            }
            for (; i < rc; i += EPI) {
                int e = i + q;
                int s = s_src_w[e];
                uint4 v = fp[(size_t)s * LPE];
                fma8(acc, s_a_w[e * H + h_of], v);
            }
        }
    }

    // cross-lane combine: edge sub-groups fold into lanes [0, LPE)
    #pragma unroll
    for (int t = 0; t < 8; t++) {
        #pragma unroll
        for (int s = LPE; s < 64; s <<= 1) acc[t] += __shfl_xor(acc[t], s);
    }
    if (lane < LPE) {
        float4 b0 = ((const float4*)bias)[lane * 2];
        float4 b1 = ((const float4*)bias)[lane * 2 + 1];
        float4 o0{acc[0] + b0.x, acc[1] + b0.y, acc[2] + b0.z, acc[3] + b0.w};
        float4 o1{acc[4] + b1.x, acc[5] + b1.y, acc[6] + b1.z, acc[7] + b1.w};
        if (RELU) {
            o0.x = fmaxf(o0.x, 0.f); o0.y = fmaxf(o0.y, 0.f);
            o0.z = fmaxf(o0.z, 0.f); o0.w = fmaxf(o0.w, 0.f);
            o1.x = fmaxf(o1.x, 0.f); o1.y = fmaxf(o1.y, 0.f);
            o1.z = fmaxf(o1.z, 0.f); o1.w = fmaxf(o1.w, 0.f);
        }
        float4* op = (float4*)out + (size_t)n * (HD / 4) + lane * 2;
        op[0] = o0;
        op[1] = o1;
    }
}

// ---------------- launch ----------------

extern "C" void kernel_launch(void* const* d_in, const int* in_sizes, int n_in,
                              void* d_out, int out_size, void* d_ws, size_t ws_size,
                              hipStream_t stream) {
    const float* feat    = (const float*)d_in[0];
    const int*   src     = (const int*)d_in[1];
    const int*   dst     = (const int*)d_in[2];
    const float* W1      = (const float*)d_in[3];
    const float* attn_l1 = (const float*)d_in[4];
    const float* attn_r1 = (const float*)d_in[5];
    const float* bias1   = (const float*)d_in[6];
    const float* W2      = (const float*)d_in[7];
    const float* attn_l2 = (const float*)d_in[8];
    const float* attn_r2 = (const float*)d_in[9];
    const float* bias2   = (const float*)d_in[10];
    float* out = (float*)d_out;

    const int N = in_sizes[0] / 256;   // 50000
    const int E = in_sizes[1];         // 800000
    const int NB = (N + 1023) / 1024;  // 49 (<= 64 for lookback wave)

    char* ws = (char*)d_ws;
    size_t o = 0;
    auto alloc = [&](size_t bytes) -> void* {
        void* p = ws + o;
        o = (o + bytes + 255) & ~(size_t)255;
        return p;
    };
    int* counts  = (int*)alloc((size_t)(N + 64) * 4);
    int* flags   = counts + N;
    int* cursor  = (int*)alloc((size_t)N * 4);
    int* offsets = (int*)alloc((size_t)(N + 1) * 4);
    int* csr_src = (int*)alloc((size_t)E * 4);
    float* wl1 = (float*)alloc(256 * 8 * 4);
    float* wl2 = (float*)alloc(256 * 2 * 4);
    float* el1 = (float*)alloc((size_t)N * 4 * 4);
    float* er1 = (float*)alloc((size_t)N * 4 * 4);
    float* el2 = (float*)alloc((size_t)N * 4);
    float* er2 = (float*)alloc((size_t)N * 4);
    unsigned short* ft1b = (unsigned short*)alloc((size_t)N * 256 * 2);
    float* h1 = (float*)alloc((size_t)N * 256 * 4);
    unsigned short* ft2b = ft1b;   // ft1b dead after layer-1 aggregation

    hipMemsetAsync(counts, 0, (size_t)(N + 64) * 4, stream);
    count_wl_k<<<1 + (E + 255) / 256, 256, 0, stream>>>(dst, counts, E,
        W1, attn_l1, attn_r1, W2, attn_l2, attn_r2, wl1, wl2);
    scan_k<<<NB, 1024, 0, stream>>>(counts, flags, offsets, cursor, N);
    fill_csr_k<<<(E + 255) / 256, 256, 0, stream>>>(src, dst, cursor, csr_src, E);

    // layer 1: H=4, D=64  (grid: by fastest for A-tile L2 reuse)
    gemm_k<1><<<dim3(4, (N + 127) / 128), 256, 0, stream>>>(feat, W1, ft1b, N, 256, 256,
                                                            wl1, el1, er1);
    fagg_k<4, 64, true><<<(N + 3) / 4, 256, 0, stream>>>(ft1b, el1, er1, offsets, csr_src,
                                                         bias1, h1, N);

    // layer 2: H=1, D=128
    gemm_k<2><<<dim3(2, (N + 127) / 128), 256, 0, stream>>>(h1, W2, ft2b, N, 256, 128,
                                                            wl2, el2, er2);
    fagg_k<1, 128, false><<<(N + 3) / 4, 256, 0, stream>>>(ft2b, el2, er2, offsets, csr_src,
                                                           bias2, out, N);
}